// Round 4
// baseline (614.376 us; speedup 1.0000x reference)
//
#include <hip/hip_runtime.h>
#include <hip/hip_cooperative_groups.h>
#include <float.h>
#include <math.h>

namespace cg = cooperative_groups;

// Problem constants
#define B_SZ 1024
#define D_SZ 8192
#define C_SZ 345
#define F_SZ 512
#define PROTO_W 0.99f

// d_out layout (float32, flat, reference return order):
//   logits   [2048][345]  @ 0
//   new_proto[345][512]   @ 706560
//   scores   [345][345]   @ 883200
//   labels   [1024]       @ 1002225  (stored as float)
//   feats    [2048][512]  @ 1003249

// ---------------- NEW-path d_ws layout -----------
#define WS_XH 0
#define WS_XL 33554432u
#define WS_WH 67108864u
#define WS_WL 75497472u
#define WS_P  83886080u
#define WS2_WFH 100663296u
#define WS2_WFL 101056512u
#define WS2_LAB 101449728u
#define WS2_NEED 101457920u
// Fh/Fl overlay the Xh region (Xh dead after gemm phase; ordered by grid.sync)
#define WS2_FH 0u
#define WS2_FL 2097152u

// ---------------- OLD-path (R6 fallback) overlay offsets ---------------------
#define WS_NEED 92274688u
#define WS_FH  0u
#define WS_FL  2097152u
#define WS_WFH 4194304u
#define WS_WFL 4587520u
#define WS_NPH 4980736u
#define WS_NPL 5373952u

typedef short bf16x8 __attribute__((ext_vector_type(8)));
typedef short short4v __attribute__((ext_vector_type(4)));
typedef short short8v __attribute__((ext_vector_type(8)));
typedef float f32x4  __attribute__((ext_vector_type(4)));

__device__ __forceinline__ void split_bf16(float x, short& hi, short& lo) {
    unsigned u = __float_as_uint(x);
    unsigned r = (u + 0x7FFFu + ((u >> 16) & 1u)) >> 16;
    hi = (short)r;
    float hf = __uint_as_float(r << 16);
    lo = (short)(__float_as_uint(x - hf) >> 16);
}
__device__ __forceinline__ float bf16_f32(short h) {
    return __uint_as_float(((unsigned)(unsigned short)h) << 16);
}

__device__ __forceinline__ void gl_lds16(const short* g, short* l) {
    __builtin_amdgcn_global_load_lds(
        (const __attribute__((address_space(1))) void*)g,
        (__attribute__((address_space(3))) void*)l, 16, 0, 0);
}

// order-preserving float -> u32 key (larger float => larger key)
__device__ __forceinline__ unsigned f2key(float v) {
    unsigned u = __float_as_uint(v);
    return (u & 0x80000000u) ? ~u : (u | 0x80000000u);
}

// Raw barrier with compiler memory fence but NO hardware counter drain.
__device__ __forceinline__ void fence_barrier() {
    asm volatile("" ::: "memory");
    __builtin_amdgcn_s_barrier();
    asm volatile("" ::: "memory");
}

#define MFMA_BF16 __builtin_amdgcn_mfma_f32_16x16x32_bf16

// 12-MFMA bf16x3 block (2x2 frags); expects sAh/sAl/sBh/sBl + acc in scope.
#define MFMA_BLOCK(IA0, IA1, IB0, IB1)                                   \
    do {                                                                 \
        bf16x8 a0h = *(const bf16x8*)&sAh[IA0];                          \
        bf16x8 a1h = *(const bf16x8*)&sAh[IA1];                          \
        bf16x8 b0h = *(const bf16x8*)&sBh[IB0];                          \
        bf16x8 b1h = *(const bf16x8*)&sBh[IB1];                          \
        bf16x8 a0l = *(const bf16x8*)&sAl[IA0];                          \
        bf16x8 a1l = *(const bf16x8*)&sAl[IA1];                          \
        bf16x8 b0l = *(const bf16x8*)&sBl[IB0];                          \
        bf16x8 b1l = *(const bf16x8*)&sBl[IB1];                          \
        acc[0][0] = MFMA_BF16(a0h, b0h, acc[0][0], 0, 0, 0);             \
        acc[0][1] = MFMA_BF16(a0h, b1h, acc[0][1], 0, 0, 0);             \
        acc[1][0] = MFMA_BF16(a1h, b0h, acc[1][0], 0, 0, 0);             \
        acc[1][1] = MFMA_BF16(a1h, b1h, acc[1][1], 0, 0, 0);             \
        acc[0][0] = MFMA_BF16(a0h, b0l, acc[0][0], 0, 0, 0);             \
        acc[0][1] = MFMA_BF16(a0h, b1l, acc[0][1], 0, 0, 0);             \
        acc[1][0] = MFMA_BF16(a1h, b0l, acc[1][0], 0, 0, 0);             \
        acc[1][1] = MFMA_BF16(a1h, b1l, acc[1][1], 0, 0, 0);             \
        acc[0][0] = MFMA_BF16(a0l, b0h, acc[0][0], 0, 0, 0);             \
        acc[0][1] = MFMA_BF16(a0l, b1h, acc[0][1], 0, 0, 0);             \
        acc[1][0] = MFMA_BF16(a1l, b0h, acc[1][0], 0, 0, 0);             \
        acc[1][1] = MFMA_BF16(a1l, b1h, acc[1][1], 0, 0, 0);             \
    } while (0)

// ---------------------------------------------------------------------------
// proto body (shared state passed as pointers into the LDS union)
// ---------------------------------------------------------------------------
__device__ __forceinline__ void proto_one(
    int c, int t, int lane, int w,
    const unsigned long long* labPack, const float* feats_q,
    const float* proto_in, const short* Wth, const short* Wtl,
    const float* b_fc, float* new_proto, float* scores, float* labels_f,
    int* rowlist, float* nprow, float* red, int* mcount, float* rinv)
{
    if (c == 0) {
#pragma unroll
        for (int j = 0; j < 2; ++j) {
            const int i = t + j * 512;
            int li = (int)(0xFFFFFFFFu - (unsigned)(labPack[i] & 0xFFFFFFFFull));
            labels_f[i] = (float)li;
        }
    }

    if (w == 0) {
        int k = 0;
#pragma unroll
        for (int ch = 0; ch < 16; ++ch) {
            unsigned long long pk = labPack[ch * 64 + lane];
            int li = (int)(0xFFFFFFFFu - (unsigned)(pk & 0xFFFFFFFFull));
            unsigned long long mask = __ballot(li == c);
            if (lane == 0) {
                while (mask) {
                    int p = __builtin_ctzll(mask);
                    mask &= mask - 1;
                    rowlist[k++] = ch * 64 + p;
                }
            }
            k = __shfl(k, 0);
        }
        if (lane == 0) *mcount = k;
    }
    __syncthreads();
    const int m = *mcount;

    float val = proto_in[(size_t)c * F_SZ + t];
    for (int k = 0; k < m; ++k)
        val = PROTO_W * val + (1.0f - PROTO_W) * feats_q[(size_t)rowlist[k] * F_SZ + t];

    float sq = val * val;
#pragma unroll
    for (int off = 32; off; off >>= 1) sq += __shfl_down(sq, off);
    if ((t & 63) == 0) red[t >> 6] = sq;
    __syncthreads();
    if (t == 0) {
        float s = 0.0f;
#pragma unroll
        for (int ww = 0; ww < 8; ++ww) s += red[ww];
        *rinv = 1.0f / sqrtf(s);
    }
    __syncthreads();
    const float v = val * (*rinv);
    new_proto[(size_t)c * F_SZ + t] = v;
    nprow[t] = v;
    __syncthreads();

    float np8[8];
#pragma unroll
    for (int j = 0; j < 8; ++j) np8[j] = nprow[lane * 8 + j];
    for (int col = w; col < C_SZ; col += 8) {
        const short8v h = *(const short8v*)&Wth[(size_t)col * F_SZ + lane * 8];
        const short8v l = *(const short8v*)&Wtl[(size_t)col * F_SZ + lane * 8];
        float p = 0.0f;
#pragma unroll
        for (int j = 0; j < 8; ++j)
            p += np8[j] * (bf16_f32(h[j]) + bf16_f32(l[j]));
#pragma unroll
        for (int off = 32; off; off >>= 1) p += __shfl_down(p, off);
        if (lane == 0) scores[(size_t)c * C_SZ + col] = p + b_fc[col];
    }
}

// ===========================================================================
// MEGA (R12): entire new-path pipeline in ONE cooperative kernel.
// grid 256 x 512 threads, 1 block/CU (128 KB LDS). Phases separated by
// grid.sync(); every block passes every sync; all block-local barriers are
// executed by all 512 threads. Numerics bit-identical to the R2 pipeline.
// NOTE: Xh/Fh alias (overlay) -> no __restrict__ on ws pointers.
// ===========================================================================
__global__ __launch_bounds__(512, 1) void mega(
    const float* img_q, const float* img_q1, const float* partial_Y,
    const float* W_enc, const float* W_fc, const float* b_fc,
    const float* proto_in,
    short* Xh, short* Xl, short* Wh, short* Wl, float* P,
    short* Wth, short* Wtl, unsigned long long* labPack,
    short* Fh, short* Fl,
    float* logits, float* new_proto, float* scores, float* labels_f,
    float* feats)
{
    cg::grid_group grid = cg::this_grid();
    __shared__ __align__(16) char LDSU[131072];

    const int bid = blockIdx.x;
    const int t = threadIdx.x;
    const int lane = t & 63;
    const int wave = t >> 6;

    // ============ P1: convert (X, W_enc, W_fc) + labPack zero ============
    if (bid < 2) labPack[bid * 512 + t] = 0ull;

    {   // X -> Xh/Xl, grid-stride: 4M float4 over 131072 threads (32 iters)
        const int HALF = (B_SZ * D_SZ) / 4;
        const int total = 2 * HALF;
        for (int i4 = bid * 512 + t; i4 < total; i4 += 256 * 512) {
            float4 v = (i4 < HALF) ? ((const float4*)img_q)[i4]
                                   : ((const float4*)img_q1)[i4 - HALF];
            short4v h, l;
            short hh, ll;
            split_bf16(v.x, hh, ll); h.x = hh; l.x = ll;
            split_bf16(v.y, hh, ll); h.y = hh; l.y = ll;
            split_bf16(v.z, hh, ll); h.z = hh; l.z = ll;
            split_bf16(v.w, hh, ll); h.w = hh; l.w = ll;
            ((short4v*)Xh)[i4] = h;
            ((short4v*)Xl)[i4] = l;
        }
    }

    {   // W_enc transpose: 1024 64x64 tile jobs, 4 per block
        float (*tile)[65] = (float(*)[65])LDSU;
        const int kr = t >> 3;
        const int cb = (t & 7) * 8;
        const int n  = t >> 3;
        const int ch = t & 7;
#pragma unroll
        for (int j = 0; j < 4; ++j) {
            const int id = bid * 4 + j;
            const int k0 = (id >> 3) * 64;
            const int n0 = (id & 7) * 64;
            __syncthreads();
            float4 v0 = *(const float4*)&W_enc[(size_t)(k0 + kr) * F_SZ + n0 + cb];
            float4 v1 = *(const float4*)&W_enc[(size_t)(k0 + kr) * F_SZ + n0 + cb + 4];
            tile[kr][cb + 0] = v0.x; tile[kr][cb + 1] = v0.y;
            tile[kr][cb + 2] = v0.z; tile[kr][cb + 3] = v0.w;
            tile[kr][cb + 4] = v1.x; tile[kr][cb + 5] = v1.y;
            tile[kr][cb + 6] = v1.z; tile[kr][cb + 7] = v1.w;
            __syncthreads();
            short8v h, l;
#pragma unroll
            for (int e = 0; e < 8; ++e) {
                short hh, ll;
                split_bf16(tile[ch * 8 + e][n], hh, ll);
                h[e] = hh; l[e] = ll;
            }
            size_t off = (size_t)(n0 + n) * D_SZ + k0 + ch * 8;
            *(short8v*)&Wh[off] = h;
            *(short8v*)&Wl[off] = l;
        }
    }

    if (bid < 48) {   // W_fc -> Wth/Wtl: 48 tile jobs, one per block
        float (*tile)[65] = (float(*)[65])LDSU;
        const int k0 = (bid & 7) * 64;
        const int c0 = (bid >> 3) * 64;
        __syncthreads();
        for (int idx = t; idx < 64 * 64; idx += 512) {
            const int kr2 = idx >> 6;
            const int cc = idx & 63;
            tile[kr2][cc] = (c0 + cc < C_SZ) ? W_fc[(size_t)(k0 + kr2) * C_SZ + c0 + cc] : 0.0f;
        }
        __syncthreads();
        const int crow = t >> 3;
        const int ch2 = t & 7;
        short8v h, l;
#pragma unroll
        for (int e = 0; e < 8; ++e) {
            short hh, ll;
            split_bf16(tile[ch2 * 8 + e][crow], hh, ll);
            h[e] = hh; l[e] = ll;
        }
        size_t off = (size_t)(c0 + crow) * F_SZ + k0 + ch2 * 8;
        *(short8v*)&Wth[off] = h;
        *(short8v*)&Wtl[off] = l;
    }

    asm volatile("s_waitcnt vmcnt(0)" ::: "memory");
    __threadfence();
    grid.sync();   // S1

    // ============ P2: gemm (v3 body, 256 blocks) ============
    {
        short (*sAh)[8192] = (short(*)[8192])(LDSU + 0);
        short (*sAl)[8192] = (short(*)[8192])(LDSU + 32768);
        short (*sBh)[8192] = (short(*)[8192])(LDSU + 65536);
        short (*sBl)[8192] = (short(*)[8192])(LDSU + 98304);
        const int ksteps = 32;

        // XCD-aware bijective swizzle (nwg = 256)
        const int logical = (bid & 7) * 32 + (bid >> 3);
        const int nt = logical & 3;
        const int mt = (logical >> 2) & 15;
        const int ks = logical >> 6;

        const int m0 = mt * 128;
        const int n0 = nt * 128;
        const int kbase = ks * ksteps * 64;

        const int arr = wave >> 1;
        const int half = wave & 1;
        const short* gbase =
            (arr == 0) ? Xh + (size_t)m0 * D_SZ :
            (arr == 1) ? Xl + (size_t)m0 * D_SZ :
            (arr == 2) ? Wh + (size_t)n0 * D_SZ :
                         Wl + (size_t)n0 * D_SZ;
        short* lb[2];
        lb[0] = ((arr == 0) ? sAh[0] : (arr == 1) ? sAl[0] : (arr == 2) ? sBh[0] : sBl[0]) + half * 4096;
        lb[1] = ((arr == 0) ? sAh[1] : (arr == 1) ? sAl[1] : (arr == 2) ? sBh[1] : sBl[1]) + half * 4096;
        const int lrow8 = lane >> 3;
        const int gchunkOff = ((lane & 7) ^ lrow8) * 8;
        const short* gsrc = gbase + (size_t)(half * 64 + lrow8) * D_SZ + kbase + gchunkOff;

        const int wr = wave >> 2;
        const int wc = wave & 3;
        const int mo = wr * 64;
        const int no = wc * 32;
        const int lr = lane & 15;
        const int lkg = lane >> 4;
        const int x7 = lr & 7;
        const int sl0 = lkg ^ x7;
        const int sl1 = (4 + lkg) ^ x7;
        int aoff[4], boff[2];
#pragma unroll
        for (int f = 0; f < 4; ++f) aoff[f] = (mo + 16 * f + lr) * 64;
#pragma unroll
        for (int g = 0; g < 2; ++g) boff[g] = (no + 16 * g + lr) * 64;

        f32x4 acc[4][2] = {};

#pragma unroll
        for (int j = 0; j < 8; ++j)
            gl_lds16(gsrc + (size_t)(8 * j) * D_SZ, lb[0] + j * 512);

        int buf = 0;
        for (int s = 0; s < ksteps; ++s) {
            if (s + 1 < ksteps) {
                short* dst = lb[buf ^ 1];
                const short* g = gsrc + (s + 1) * 64;
#pragma unroll
                for (int j = 0; j < 8; ++j)
                    gl_lds16(g + (size_t)(8 * j) * D_SZ, dst + j * 512);
                asm volatile("s_waitcnt vmcnt(8)" ::: "memory");
            } else {
                asm volatile("s_waitcnt vmcnt(0)" ::: "memory");
            }
            fence_barrier();

            const short* pAh = sAh[buf];
            const short* pAl = sAl[buf];
            const short* pBh = sBh[buf];
            const short* pBl = sBl[buf];

            {
                bf16x8 ah[4], al[4], bh[2], bl_[2];
#pragma unroll
                for (int f = 0; f < 4; ++f) {
                    ah[f] = *(const bf16x8*)&pAh[aoff[f] + sl0 * 8];
                    al[f] = *(const bf16x8*)&pAl[aoff[f] + sl0 * 8];
                }
#pragma unroll
                for (int g = 0; g < 2; ++g) {
                    bh[g]  = *(const bf16x8*)&pBh[boff[g] + sl0 * 8];
                    bl_[g] = *(const bf16x8*)&pBl[boff[g] + sl0 * 8];
                }
                __builtin_amdgcn_s_setprio(1);
#pragma unroll
                for (int f = 0; f < 4; ++f)
#pragma unroll
                    for (int g = 0; g < 2; ++g)
                        acc[f][g] = MFMA_BF16(ah[f], bh[g], acc[f][g], 0, 0, 0);
#pragma unroll
                for (int f = 0; f < 4; ++f)
#pragma unroll
                    for (int g = 0; g < 2; ++g)
                        acc[f][g] = MFMA_BF16(ah[f], bl_[g], acc[f][g], 0, 0, 0);
#pragma unroll
                for (int f = 0; f < 4; ++f)
#pragma unroll
                    for (int g = 0; g < 2; ++g)
                        acc[f][g] = MFMA_BF16(al[f], bh[g], acc[f][g], 0, 0, 0);
                __builtin_amdgcn_s_setprio(0);
            }
            fence_barrier();

            {
                bf16x8 ah[4], al[4], bh[2], bl_[2];
#pragma unroll
                for (int f = 0; f < 4; ++f) {
                    ah[f] = *(const bf16x8*)&pAh[aoff[f] + sl1 * 8];
                    al[f] = *(const bf16x8*)&pAl[aoff[f] + sl1 * 8];
                }
#pragma unroll
                for (int g = 0; g < 2; ++g) {
                    bh[g]  = *(const bf16x8*)&pBh[boff[g] + sl1 * 8];
                    bl_[g] = *(const bf16x8*)&pBl[boff[g] + sl1 * 8];
                }
                __builtin_amdgcn_s_setprio(1);
#pragma unroll
                for (int f = 0; f < 4; ++f)
#pragma unroll
                    for (int g = 0; g < 2; ++g)
                        acc[f][g] = MFMA_BF16(ah[f], bh[g], acc[f][g], 0, 0, 0);
#pragma unroll
                for (int f = 0; f < 4; ++f)
#pragma unroll
                    for (int g = 0; g < 2; ++g)
                        acc[f][g] = MFMA_BF16(ah[f], bl_[g], acc[f][g], 0, 0, 0);
#pragma unroll
                for (int f = 0; f < 4; ++f)
#pragma unroll
                    for (int g = 0; g < 2; ++g)
                        acc[f][g] = MFMA_BF16(al[f], bh[g], acc[f][g], 0, 0, 0);
                __builtin_amdgcn_s_setprio(0);
            }
            fence_barrier();
            buf ^= 1;
        }

        float* Pout = P + (size_t)ks * (2048u * 512u);
#pragma unroll
        for (int f = 0; f < 4; ++f)
#pragma unroll
            for (int g = 0; g < 2; ++g) {
                const int col  = n0 + no + 16 * g + (lane & 15);
                const int row0 = m0 + mo + 16 * f + (lane >> 4) * 4;
#pragma unroll
                for (int r = 0; r < 4; ++r)
                    Pout[(size_t)(row0 + r) * F_SZ + col] = acc[f][g][r];
            }
    }

    asm volatile("s_waitcnt vmcnt(0)" ::: "memory");
    __threadfence();
    grid.sync();   // S2

    // ============ P3: reduce 4 P slices -> feats + Fh/Fl (bit-identical) ====
    {
        const int n4 = (2048 * 512) / 4;
        for (int i4 = bid * 512 + t; i4 < n4; i4 += 256 * 512) {
            float4 a = ((const float4*)P)[i4];
#pragma unroll
            for (int sl = 1; sl < 4; ++sl) {
                float4 b = ((const float4*)(P + (size_t)sl * (2048u * 512u)))[i4];
                a.x += b.x; a.y += b.y; a.z += b.z; a.w += b.w;
            }
            ((float4*)feats)[i4] = a;
            float v[4] = {a.x, a.y, a.z, a.w};
            short4v h, l;
            short hh, ll;
#pragma unroll
            for (int e = 0; e < 4; ++e) {
                split_bf16(v[e], hh, ll); h[e] = hh; l[e] = ll;
            }
            ((short4v*)Fh)[i4] = h;
            ((short4v*)Fl)[i4] = l;
        }
    }

    asm volatile("s_waitcnt vmcnt(0)" ::: "memory");
    __threadfence();
    grid.sync();   // S3

    // ============ P4: fc logits + masked argmax (blocks 0..191, 8 waves) ====
    if (bid < 192) {
        short* dAh = (short*)(LDSU + 0);       // [2][4096]
        short* dAl = (short*)(LDSU + 16384);
        short* dBh = (short*)(LDSU + 32768);
        short* dBl = (short*)(LDSU + 49152);

        const int n0 = (bid % 6) * 64;
        const int m0 = (bid / 6) * 64;

        const int lrow8 = lane >> 3;
        const int colOff = ((lane & 7) ^ lrow8) * 8;
        const int arr = wave >> 1;
        const int halfw = wave & 1;
        const short* gsrc = (arr == 0) ? Fh : (arr == 1) ? Fl
                          : (arr == 2) ? Wth : Wtl;
        const int rbase = (arr < 2) ? m0 : n0;
        short* abase = (arr == 0) ? dAh : (arr == 1) ? dAl : (arr == 2) ? dBh : dBl;
        short* lb[2];
        lb[0] = abase + halfw * 2048;
        lb[1] = abase + 4096 + halfw * 2048;
        const short* gb = gsrc + (size_t)(rbase + halfw * 32 + lrow8) * F_SZ + colOff;

        const int mo = (wave >> 1) * 16;
        const int no_ = (wave & 1) * 32;
        const int lr = lane & 15;
        const int lkg = lane >> 4;
        const int x7 = lr & 7;
        const int sl0 = lkg ^ x7;
        const int sl1 = (4 + lkg) ^ x7;
        const int ra  = (mo + lr) * 64;
        const int rb0 = (no_ + lr) * 64;
        const int rb1 = (no_ + 16 + lr) * 64;

        f32x4 acc0 = {}, acc1 = {};

#pragma unroll
        for (int j = 0; j < 4; ++j)
            gl_lds16(gb + (size_t)(8 * j) * F_SZ, lb[0] + j * 512);

        int buf = 0;
        for (int s = 0; s < 8; ++s) {
            if (s + 1 < 8) {
                short* dst = lb[buf ^ 1];
                const short* g = gb + (s + 1) * 64;
#pragma unroll
                for (int j = 0; j < 4; ++j)
                    gl_lds16(g + (size_t)(8 * j) * F_SZ, dst + j * 512);
                asm volatile("s_waitcnt vmcnt(4)" ::: "memory");
            } else {
                asm volatile("s_waitcnt vmcnt(0)" ::: "memory");
            }
            fence_barrier();
            const short* pAh = dAh + buf * 4096;
            const short* pAl = dAl + buf * 4096;
            const short* pBh = dBh + buf * 4096;
            const short* pBl = dBl + buf * 4096;
            __builtin_amdgcn_s_setprio(1);
#pragma unroll
            for (int ksub = 0; ksub < 2; ++ksub) {
                const int sl = ksub ? sl1 : sl0;
                bf16x8 ah  = *(const bf16x8*)&pAh[ra + sl * 8];
                bf16x8 al  = *(const bf16x8*)&pAl[ra + sl * 8];
                bf16x8 b0h = *(const bf16x8*)&pBh[rb0 + sl * 8];
                bf16x8 b1h = *(const bf16x8*)&pBh[rb1 + sl * 8];
                bf16x8 b0l = *(const bf16x8*)&pBl[rb0 + sl * 8];
                bf16x8 b1l = *(const bf16x8*)&pBl[rb1 + sl * 8];
                acc0 = MFMA_BF16(ah, b0h, acc0, 0, 0, 0);
                acc1 = MFMA_BF16(ah, b1h, acc1, 0, 0, 0);
                acc0 = MFMA_BF16(ah, b0l, acc0, 0, 0, 0);
                acc1 = MFMA_BF16(ah, b1l, acc1, 0, 0, 0);
                acc0 = MFMA_BF16(al, b0h, acc0, 0, 0, 0);
                acc1 = MFMA_BF16(al, b1h, acc1, 0, 0, 0);
            }
            __builtin_amdgcn_s_setprio(0);
            fence_barrier();
            buf ^= 1;
        }

        const bool doArg = (m0 < B_SZ);
#pragma unroll
        for (int r = 0; r < 4; ++r) {
            const int row = m0 + mo + lkg * 4 + r;
            unsigned long long best = 0;
#pragma unroll
            for (int g = 0; g < 2; ++g) {
                const int col = n0 + no_ + g * 16 + lr;
                if (col < C_SZ) {
                    const float v = (g ? acc1[r] : acc0[r]) + b_fc[col];
                    logits[(size_t)row * C_SZ + col] = v;
                    if (doArg && partial_Y[(size_t)row * C_SZ + col] != 0.0f) {
                        unsigned long long pk = ((unsigned long long)f2key(v) << 32)
                                              | (unsigned long long)(0xFFFFFFFFu - (unsigned)col);
                        if (pk > best) best = pk;
                    }
                }
            }
            if (doArg) {
#pragma unroll
                for (int mm = 1; mm < 16; mm <<= 1) {
                    unsigned long long o = __shfl_xor(best, mm);
                    if (o > best) best = o;
                }
                if (lr == 0 && best != 0)
                    atomicMax(&labPack[row], best);
            }
        }
    }

    asm volatile("s_waitcnt vmcnt(0)" ::: "memory");
    __threadfence();
    grid.sync();   // S4

    // ============ P5: proto update + scores (<=2 classes per block) ========
    {
        int*   rowlist = (int*)LDSU;
        float* nprow   = (float*)(LDSU + 4096);
        float* red     = (float*)(LDSU + 6144);
        int*   mcount  = (int*)(LDSU + 6176);
        float* rinv    = (float*)(LDSU + 6180);

        // rep 0: c = bid (all < 345)
        proto_one(bid, t, lane, wave, labPack, feats, proto_in, Wth, Wtl,
                  b_fc, new_proto, scores, labels_f,
                  rowlist, nprow, red, mcount, rinv);
        // rep 1: c = bid + 256 (blocks 0..88)
        const int c2 = bid + 256;
        if (c2 < C_SZ) {
            __syncthreads();
            proto_one(c2, t, lane, wave, labPack, feats, proto_in, Wth, Wtl,
                      b_fc, new_proto, scores, labels_f,
                      rowlist, nprow, red, mcount, rinv);
        }
    }
}

// ===========================================================================
// OLD-path kernels (R6-proven fallback; used when ws < WS2_NEED)
// ===========================================================================
__global__ __launch_bounds__(256) void convert_all(
    const float* __restrict__ img_q, const float* __restrict__ img_q1,
    const float* __restrict__ W_enc, const float* __restrict__ W_fc,
    short* __restrict__ Xh, short* __restrict__ Xl,
    short* __restrict__ Wh, short* __restrict__ Wl,
    short* __restrict__ Wth, short* __restrict__ Wtl,
    unsigned long long* __restrict__ labPack)
{
    __shared__ float tile[64][65];
    const int bid = blockIdx.x;
    const int t = threadIdx.x;

    if (labPack && bid < 4)
        labPack[bid * 256 + t] = 0ull;

    if (bid < 1024) {
        const int HALF = (B_SZ * D_SZ) / 4;
        const int total = 2 * HALF;
        for (int i4 = bid * 256 + t; i4 < total; i4 += 1024 * 256) {
            float4 v = (i4 < HALF) ? ((const float4*)img_q)[i4]
                                   : ((const float4*)img_q1)[i4 - HALF];
            short4v h, l;
            short hh, ll;
            split_bf16(v.x, hh, ll); h.x = hh; l.x = ll;
            split_bf16(v.y, hh, ll); h.y = hh; l.y = ll;
            split_bf16(v.z, hh, ll); h.z = hh; l.z = ll;
            split_bf16(v.w, hh, ll); h.w = hh; l.w = ll;
            ((short4v*)Xh)[i4] = h;
            ((short4v*)Xl)[i4] = l;
        }
    } else if (bid < 2048) {
        const int id = bid - 1024;
        const int k0 = (id >> 3) * 64;
        const int n0 = (id & 7) * 64;
        {
            const int kr = t >> 2;
            const int cb = (t & 3) * 16;
#pragma unroll
            for (int j = 0; j < 4; ++j) {
                float4 v = *(const float4*)&W_enc[(size_t)(k0 + kr) * F_SZ + n0 + cb + j * 4];
                tile[kr][cb + j * 4 + 0] = v.x;
                tile[kr][cb + j * 4 + 1] = v.y;
                tile[kr][cb + j * 4 + 2] = v.z;
                tile[kr][cb + j * 4 + 3] = v.w;
            }
        }
        __syncthreads();
        const int n = t >> 2;
#pragma unroll
        for (int cc = 0; cc < 2; ++cc) {
            const int ch = (t & 3) * 2 + cc;
            short8v h, l;
#pragma unroll
            for (int e = 0; e < 8; ++e) {
                short hh, ll;
                split_bf16(tile[ch * 8 + e][n], hh, ll);
                h[e] = hh; l[e] = ll;
            }
            size_t off = (size_t)(n0 + n) * D_SZ + k0 + ch * 8;
            *(short8v*)&Wh[off] = h;
            *(short8v*)&Wl[off] = l;
        }
    } else {
        const int id = bid - 2048;
        const int k0 = (id & 7) * 64;
        const int c0 = (id >> 3) * 64;
        for (int idx = t; idx < 64 * 64; idx += 256) {
            const int kr = idx >> 6;
            const int cc = idx & 63;
            tile[kr][cc] = (c0 + cc < C_SZ) ? W_fc[(size_t)(k0 + kr) * C_SZ + c0 + cc] : 0.0f;
        }
        __syncthreads();
        const int crow = t >> 2;
#pragma unroll
        for (int cc2 = 0; cc2 < 2; ++cc2) {
            const int ch = (t & 3) * 2 + cc2;
            short8v h, l;
#pragma unroll
            for (int e = 0; e < 8; ++e) {
                short hh, ll;
                split_bf16(tile[ch * 8 + e][crow], hh, ll);
                h[e] = hh; l[e] = ll;
            }
            size_t off = (size_t)(c0 + crow) * F_SZ + k0 + ch * 8;
            *(short8v*)&Wth[off] = h;
            *(short8v*)&Wtl[off] = l;
        }
    }
}

__global__ __launch_bounds__(256, 1) void gemm_ws128(
    const short* __restrict__ Xh, const short* __restrict__ Xl,
    const short* __restrict__ Wh, const short* __restrict__ Wl,
    float* __restrict__ P, int ksteps)
{
    __shared__ __align__(16) short sAh[2][8192];
    __shared__ __align__(16) short sAl[2][8192];
    __shared__ __align__(16) short sBh[2][8192];
    __shared__ __align__(16) short sBl[2][8192];

    const int t = threadIdx.x;
    const int lane = t & 63;
    const int wave = t >> 6;
    const int nt = blockIdx.x;
    const int mt = blockIdx.y;
    const int ks = blockIdx.z;
    const int m0 = mt * 128;
    const int n0 = nt * 128;
    const int kbase = ks * ksteps * 64;

    const short* gbase =
        (wave == 0) ? Xh + (size_t)m0 * D_SZ :
        (wave == 1) ? Xl + (size_t)m0 * D_SZ :
        (wave == 2) ? Wh + (size_t)n0 * D_SZ :
                      Wl + (size_t)n0 * D_SZ;
    short* lb[2];
    lb[0] = (wave == 0) ? sAh[0] : (wave == 1) ? sAl[0] : (wave == 2) ? sBh[0] : sBl[0];
    lb[1] = (wave == 0) ? sAh[1] : (wave == 1) ? sAl[1] : (wave == 2) ? sBh[1] : sBl[1];
    const int lrow8 = lane >> 3;
    const int gchunkOff = ((lane & 7) ^ lrow8) * 8;
    const short* gsrc = gbase + (size_t)lrow8 * D_SZ + kbase + gchunkOff;

    const int mo = (wave >> 1) * 64;
    const int no = (wave & 1) * 64;
    const int lr = lane & 15;
    const int lkg = lane >> 4;
    const int x7 = lr & 7;
    const int sl0 = lkg ^ x7;
    const int sl1 = (4 + lkg) ^ x7;
    int aoff[4], boff[4];
#pragma unroll
    for (int f = 0; f < 4; ++f) {
        aoff[f] = (mo + 16 * f + lr) * 64;
        boff[f] = (no + 16 * f + lr) * 64;
    }

    f32x4 acc[4][4] = {};

#pragma unroll
    for (int j = 0; j < 16; ++j)
        gl_lds16(gsrc + (size_t)(8 * j) * D_SZ, lb[0] + j * 512);

    int buf = 0;
    for (int s = 0; s < ksteps; ++s) {
        if (s + 1 < ksteps) {
            short* dst = lb[buf ^ 1];
            const short* g = gsrc + (s + 1) * 64;
#pragma unroll
            for (int j = 0; j < 16; ++j)
                gl_lds16(g + (size_t)(8 * j) * D_SZ, dst + j * 512);
            asm volatile("s_waitcnt vmcnt(16)" ::: "memory");
        } else {
            asm volatile("s_waitcnt vmcnt(0)" ::: "memory");
        }
        fence_barrier();

        __builtin_amdgcn_s_setprio(1);
        {
            const short* pAh = sAh[buf];
            const short* pAl = sAl[buf];
            const short* pBh = sBh[buf];
            const short* pBl = sBl[buf];
#pragma unroll
            for (int ksub = 0; ksub < 2; ++ksub) {
                const int sl = ksub ? sl1 : sl0;
                bf16x8 ah[4], al[4], bh[4], blo[4];
#pragma unroll
                for (int f = 0; f < 4; ++f) {
                    ah[f]  = *(const bf16x8*)&pAh[aoff[f] + sl * 8];
                    al[f]  = *(const bf16x8*)&pAl[aoff[f] + sl * 8];
                }
#pragma unroll
                for (int g = 0; g < 4; ++g) {
                    bh[g]  = *(const bf16x8*)&pBh[boff[g] + sl * 8];
                    blo[g] = *(const bf16x8*)&pBl[boff[g] + sl * 8];
                }
#pragma unroll
                for (int f = 0; f < 4; ++f)
#pragma unroll
                    for (int g = 0; g < 4; ++g)
                        acc[f][g] = MFMA_BF16(ah[f], bh[g], acc[f][g], 0, 0, 0);
#pragma unroll
                for (int f = 0; f < 4; ++f)
#pragma unroll
                    for (int g = 0; g < 4; ++g)
                        acc[f][g] = MFMA_BF16(ah[f], blo[g], acc[f][g], 0, 0, 0);
#pragma unroll
                for (int f = 0; f < 4; ++f)
#pragma unroll
                    for (int g = 0; g < 4; ++g)
                        acc[f][g] = MFMA_BF16(al[f], bh[g], acc[f][g], 0, 0, 0);
            }
        }
        __builtin_amdgcn_s_setprio(0);
        fence_barrier();
        buf ^= 1;
    }

    float* Pout = P + (size_t)ks * (2048u * 512u);
#pragma unroll
    for (int f = 0; f < 4; ++f)
#pragma unroll
        for (int g = 0; g < 4; ++g) {
            const int col  = n0 + no + 16 * g + (lane & 15);
            const int row0 = m0 + mo + 16 * f + (lane >> 4) * 4;
#pragma unroll
            for (int r = 0; r < 4; ++r)
                Pout[(size_t)(row0 + r) * F_SZ + col] = acc[f][g][r];
        }
}

__global__ __launch_bounds__(256) void reduce_feats_split(
    const float* __restrict__ P, float* __restrict__ feats,
    short* __restrict__ Fh, short* __restrict__ Fl,
    const float* __restrict__ W_fc,
    short* __restrict__ Wth, short* __restrict__ Wtl)
{
    const int bid = blockIdx.x;
    const int t = threadIdx.x;
    if (bid < 1024) {
        const int n4 = (2048 * 512) / 4;
        const float* P1 = P + 2048 * 512;
        for (int i4 = bid * 256 + t; i4 < n4; i4 += 1024 * 256) {
            float4 a = ((const float4*)P)[i4];
            float4 b = ((const float4*)P1)[i4];
            float v[4] = {a.x + b.x, a.y + b.y, a.z + b.z, a.w + b.w};
            short4v h, l;
            short hh, ll;
#pragma unroll
            for (int e = 0; e < 4; ++e) {
                feats[i4 * 4 + e] = v[e];
                split_bf16(v[e], hh, ll); h[e] = hh; l[e] = ll;
            }
            ((short4v*)Fh)[i4] = h;
            ((short4v*)Fl)[i4] = l;
        }
    } else {
        __shared__ float tile[64][65];
        const int id = bid - 1024;
        const int k0 = (id & 7) * 64;
        const int c0 = (id >> 3) * 64;
        for (int idx = t; idx < 64 * 64; idx += 256) {
            const int kr = idx >> 6;
            const int cc = idx & 63;
            tile[kr][cc] = (c0 + cc < C_SZ) ? W_fc[(size_t)(k0 + kr) * C_SZ + c0 + cc] : 0.0f;
        }
        __syncthreads();
        const int crow = t >> 2;
#pragma unroll
        for (int cc2 = 0; cc2 < 2; ++cc2) {
            const int ch = (t & 3) * 2 + cc2;
            short8v h, l;
#pragma unroll
            for (int e = 0; e < 8; ++e) {
                short hh, ll;
                split_bf16(tile[ch * 8 + e][crow], hh, ll);
                h[e] = hh; l[e] = ll;
            }
            size_t off = (size_t)(c0 + crow) * F_SZ + k0 + ch * 8;
            *(short8v*)&Wth[off] = h;
            *(short8v*)&Wtl[off] = l;
        }
    }
}

__global__ __launch_bounds__(256) void gemm_fc(
    const short* __restrict__ Ah, const short* __restrict__ Al,
    const short* __restrict__ Bh, const short* __restrict__ Bl,
    const float* __restrict__ bias, float* __restrict__ Cout, int M)
{
    __shared__ __align__(16) short sAh[4096];
    __shared__ __align__(16) short sAl[4096];
    __shared__ __align__(16) short sBh[4096];
    __shared__ __align__(16) short sBl[4096];

    const int t = threadIdx.x;
    const int lane = t & 63;
    const int wave = t >> 6;
    const int n0 = blockIdx.x * 64;
    const int m0 = blockIdx.y * 64;

    const int lrow8 = lane >> 3;
    const int colOff = ((lane & 7) ^ lrow8) * 8;

    short* lbase = (wave == 0) ? sAh : (wave == 1) ? sAl : (wave == 2) ? sBh : sBl;
    const short* gA = (wave == 1) ? Al : Ah;
    const short* gB = (wave == 3) ? Bl : Bh;
    const bool isA = wave < 2;

    const int mo = (wave >> 1) * 32;
    const int no = (wave & 1) * 32;
    const int lr = lane & 15;
    const int lkg = lane >> 4;
    const int x7 = lr & 7;
    const int sl0 = (0 + lkg) ^ x7;
    const int sl1 = (4 + lkg) ^ x7;
    const int ra0 = (mo + lr) * 64,      ra1 = (mo + 16 + lr) * 64;
    const int rb0 = (no + lr) * 64,      rb1 = (no + 16 + lr) * 64;
    const int a00 = ra0 + sl0 * 8, a01 = ra0 + sl1 * 8;
    const int a10 = ra1 + sl0 * 8, a11 = ra1 + sl1 * 8;
    const int b00 = rb0 + sl0 * 8, b01 = rb0 + sl1 * 8;
    const int b10 = rb1 + sl0 * 8, b11 = rb1 + sl1 * 8;

    f32x4 acc[2][2] = {};

    for (int s = 0; s < 8; ++s) {
        __syncthreads();
        if (isA) {
#pragma unroll
            for (int j = 0; j < 8; ++j) {
                int row = m0 + lrow8 + 8 * j;
                if (row > M - 1) row = M - 1;
                gl_lds16(gA + (size_t)row * F_SZ + s * 64 + colOff, lbase + j * 512);
            }
        } else {
#pragma unroll
            for (int j = 0; j < 8; ++j) {
                int row = n0 + lrow8 + 8 * j;
                gl_lds16(gB + (size_t)row * F_SZ + s * 64 + colOff, lbase + j * 512);
            }
        }
        __syncthreads();
        MFMA_BLOCK(a00, a10, b00, b10);
        MFMA_BLOCK(a01, a11, b01, b11);
    }

#pragma unroll
    for (int f = 0; f < 2; ++f)
#pragma unroll
        for (int g = 0; g < 2; ++g) {
            const int col  = n0 + no + g * 16 + (lane & 15);
            if (col >= C_SZ) continue;
            const float bb = bias[col];
            const int row0 = m0 + mo + f * 16 + (lane >> 4) * 4;
#pragma unroll
            for (int r = 0; r < 4; ++r) {
                const int row = row0 + r;
                if (row < M)
                    Cout[(size_t)row * C_SZ + col] = acc[f][g][r] + bb;
            }
        }
}

__global__ __launch_bounds__(64) void argmax_labels(
    const float* __restrict__ logits, const float* __restrict__ partial_Y,
    float* __restrict__ labels_f)
{
    const int i = blockIdx.x;
    const int lane = threadIdx.x;
    float best = -FLT_MAX;
    int bidx = C_SZ;
    for (int c = lane; c < C_SZ; c += 64) {
        if (partial_Y[(size_t)i * C_SZ + c] != 0.0f) {
            float v = logits[(size_t)i * C_SZ + c];
            if (v > best || (v == best && c < bidx)) { best = v; bidx = c; }
        }
    }
#pragma unroll
    for (int off = 32; off; off >>= 1) {
        float ov = __shfl_down(best, off);
        int oi = __shfl_down(bidx, off);
        if (ov > best || (ov == best && oi < bidx)) { best = ov; bidx = oi; }
    }
    if (lane == 0) labels_f[i] = (float)bidx;
}

__global__ __launch_bounds__(512) void proto_update(
    const float* __restrict__ labels_f, const float* __restrict__ feats_q,
    const float* __restrict__ proto, float* __restrict__ new_proto,
    short* __restrict__ NPh, short* __restrict__ NPl)
{
    __shared__ int lab[B_SZ];
    __shared__ float red[8];
    __shared__ float rinv_s;
    const int c = blockIdx.x;
    const int t = threadIdx.x;
    for (int i = t; i < B_SZ; i += 512) lab[i] = (int)labels_f[i];
    __syncthreads();
    float val = proto[(size_t)c * F_SZ + t];
    for (int i = 0; i < B_SZ; ++i) {
        if (lab[i] == c)
            val = PROTO_W * val + (1.0f - PROTO_W) * feats_q[(size_t)i * F_SZ + t];
    }
    float sq = val * val;
#pragma unroll
    for (int off = 32; off; off >>= 1) sq += __shfl_down(sq, off);
    if ((t & 63) == 0) red[t >> 6] = sq;
    __syncthreads();
    if (t == 0) {
        float s = 0.0f;
#pragma unroll
        for (int w = 0; w < 8; ++w) s += red[w];
        rinv_s = 1.0f / sqrtf(s);
    }
    __syncthreads();
    const float v = val * rinv_s;
    new_proto[(size_t)c * F_SZ + t] = v;
    if (NPh) {
        short hh, ll;
        split_bf16(v, hh, ll);
        NPh[(size_t)c * F_SZ + t] = hh;
        NPl[(size_t)c * F_SZ + t] = ll;
    }
}

// ---------------------------------------------------------------------------
extern "C" void kernel_launch(void* const* d_in, const int* in_sizes, int n_in,
                              void* d_out, int out_size, void* d_ws, size_t ws_size,
                              hipStream_t stream)
{
    const float* img_q     = (const float*)d_in[0];
    const float* img_q1    = (const float*)d_in[1];
    const float* partial_Y = (const float*)d_in[2];
    const float* W_enc     = (const float*)d_in[3];
    const float* W_fc      = (const float*)d_in[4];
    const float* b_fc      = (const float*)d_in[5];
    const float* proto     = (const float*)d_in[6];

    float* out       = (float*)d_out;
    float* logits    = out;            // [2048][345]
    float* new_proto = out + 706560;   // [345][512]
    float* scores    = out + 883200;   // [345][345]
    float* labels_f  = out + 1002225;  // [1024]
    float* feats     = out + 1003249;  // [2048][512]

    char* ws = (char*)d_ws;
    short* Xh = (short*)(ws + WS_XH);
    short* Xl = (short*)(ws + WS_XL);
    short* Wh = (short*)(ws + WS_WH);
    short* Wl = (short*)(ws + WS_WL);
    float* P  = (float*)(ws + WS_P);

    if (ws_size >= (size_t)WS2_NEED) {
        short* Wth = (short*)(ws + WS2_WFH);
        short* Wtl = (short*)(ws + WS2_WFL);
        unsigned long long* labPack = (unsigned long long*)(ws + WS2_LAB);
        short* Fh = (short*)(ws + WS2_FH);   // overlays Xh (ordered by grid.sync)
        short* Fl = (short*)(ws + WS2_FL);

        void* args[] = {
            (void*)&img_q, (void*)&img_q1, (void*)&partial_Y,
            (void*)&W_enc, (void*)&W_fc, (void*)&b_fc, (void*)&proto,
            (void*)&Xh, (void*)&Xl, (void*)&Wh, (void*)&Wl, (void*)&P,
            (void*)&Wth, (void*)&Wtl, (void*)&labPack,
            (void*)&Fh, (void*)&Fl,
            (void*)&logits, (void*)&new_proto, (void*)&scores,
            (void*)&labels_f, (void*)&feats
        };
        hipLaunchCooperativeKernel((const void*)mega, dim3(256), dim3(512),
                                   args, 0, stream);
    } else {
        short* Fh  = (short*)(ws + WS_FH);
        short* Fl  = (short*)(ws + WS_FL);
        short* Wth = (short*)(ws + WS_WFH);
        short* Wtl = (short*)(ws + WS_WFL);
        short* NPh = (short*)(ws + WS_NPH);
        short* NPl = (short*)(ws + WS_NPL);

        hipLaunchKernelGGL(convert_all, dim3(2048), dim3(256), 0, stream,
                           img_q, img_q1, W_enc, W_fc, Xh, Xl, Wh, Wl,
                           (short*)nullptr, (short*)nullptr,
                           (unsigned long long*)nullptr);
        hipLaunchKernelGGL(gemm_ws128, dim3(4, 16, 2), dim3(256), 0, stream,
                           Xh, Xl, Wh, Wl, P, 64);
        hipLaunchKernelGGL(reduce_feats_split, dim3(1072), dim3(256), 0, stream,
                           P, feats, Fh, Fl, W_fc, Wth, Wtl);
        hipLaunchKernelGGL(gemm_fc, dim3(6, 32), dim3(256), 0, stream,
                           Fh, Fl, Wth, Wtl, b_fc, logits, 2048);
        hipLaunchKernelGGL(argmax_labels, dim3(1024), dim3(64), 0, stream,
                           logits, partial_Y, labels_f);
        hipLaunchKernelGGL(proto_update, dim3(345), dim3(512), 0, stream,
                           labels_f, feats, proto, new_proto, NPh, NPl);
        hipLaunchKernelGGL(gemm_fc, dim3(6, 6), dim3(256), 0, stream,
                           NPh, NPl, Wth, Wtl, b_fc, scores, C_SZ);
    }
}

// Round 5
// 253.260 us; speedup vs baseline: 2.4259x; 2.4259x over previous
//
#include <hip/hip_runtime.h>
#include <float.h>
#include <math.h>

// Problem constants
#define B_SZ 1024
#define D_SZ 8192
#define C_SZ 345
#define F_SZ 512
#define PROTO_W 0.99f

// d_out layout (float32, flat, reference return order):
//   logits   [2048][345]  @ 0
//   new_proto[345][512]   @ 706560
//   scores   [345][345]   @ 883200
//   labels   [1024]       @ 1002225  (stored as float)
//   feats    [2048][512]  @ 1003249

// ---------------- NEW-path d_ws layout (NO overlay for live data) -----------
// Xh/Xl/Wh/Wl now hold PACKED tiles (R13): A arrays [mt*128+kstep][8192 sh],
// B arrays [nt*128+kstep][8192 sh]; same total sizes as before.
#define WS_XH 0
#define WS_XL 33554432u
#define WS_WH 67108864u
#define WS_WL 75497472u
#define WS_P  83886080u
#define WS2_WFH 100663296u
#define WS2_WFL 101056512u
#define WS2_LAB 101449728u
#define WS2_NEED 101457920u

// ---------------- OLD-path (R6 fallback) overlay offsets ---------------------
#define WS_NEED 92274688u
#define WS_FH  0u
#define WS_FL  2097152u
#define WS_WFH 4194304u
#define WS_WFL 4587520u
#define WS_NPH 4980736u
#define WS_NPL 5373952u

typedef short bf16x8 __attribute__((ext_vector_type(8)));
typedef short short4v __attribute__((ext_vector_type(4)));
typedef short short8v __attribute__((ext_vector_type(8)));
typedef float f32x4  __attribute__((ext_vector_type(4)));

__device__ __forceinline__ void split_bf16(float x, short& hi, short& lo) {
    unsigned u = __float_as_uint(x);
    unsigned r = (u + 0x7FFFu + ((u >> 16) & 1u)) >> 16;
    hi = (short)r;
    float hf = __uint_as_float(r << 16);
    lo = (short)(__float_as_uint(x - hf) >> 16);
}
__device__ __forceinline__ float bf16_f32(short h) {
    return __uint_as_float(((unsigned)(unsigned short)h) << 16);
}

__device__ __forceinline__ void gl_lds16(const short* g, short* l) {
    __builtin_amdgcn_global_load_lds(
        (const __attribute__((address_space(1))) void*)g,
        (__attribute__((address_space(3))) void*)l, 16, 0, 0);
}

// order-preserving float -> u32 key (larger float => larger key)
__device__ __forceinline__ unsigned f2key(float v) {
    unsigned u = __float_as_uint(v);
    return (u & 0x80000000u) ? ~u : (u | 0x80000000u);
}

// Raw barrier with compiler memory fence but NO hardware counter drain.
__device__ __forceinline__ void fence_barrier() {
    asm volatile("" ::: "memory");
    __builtin_amdgcn_s_barrier();
    asm volatile("" ::: "memory");
}

#define MFMA_BF16 __builtin_amdgcn_mfma_f32_16x16x32_bf16

// 12-MFMA bf16x3 block (2x2 frags); expects sAh/sAl/sBh/sBl + acc in scope.
#define MFMA_BLOCK(IA0, IA1, IB0, IB1)                                   \
    do {                                                                 \
        bf16x8 a0h = *(const bf16x8*)&sAh[IA0];                          \
        bf16x8 a1h = *(const bf16x8*)&sAh[IA1];                          \
        bf16x8 b0h = *(const bf16x8*)&sBh[IB0];                          \
        bf16x8 b1h = *(const bf16x8*)&sBh[IB1];                          \
        bf16x8 a0l = *(const bf16x8*)&sAl[IA0];                          \
        bf16x8 a1l = *(const bf16x8*)&sAl[IA1];                          \
        bf16x8 b0l = *(const bf16x8*)&sBl[IB0];                          \
        bf16x8 b1l = *(const bf16x8*)&sBl[IB1];                          \
        acc[0][0] = MFMA_BF16(a0h, b0h, acc[0][0], 0, 0, 0);             \
        acc[0][1] = MFMA_BF16(a0h, b1h, acc[0][1], 0, 0, 0);             \
        acc[1][0] = MFMA_BF16(a1h, b0h, acc[1][0], 0, 0, 0);             \
        acc[1][1] = MFMA_BF16(a1h, b1h, acc[1][1], 0, 0, 0);             \
        acc[0][0] = MFMA_BF16(a0h, b0l, acc[0][0], 0, 0, 0);             \
        acc[0][1] = MFMA_BF16(a0h, b1l, acc[0][1], 0, 0, 0);             \
        acc[1][0] = MFMA_BF16(a1h, b0l, acc[1][0], 0, 0, 0);             \
        acc[1][1] = MFMA_BF16(a1h, b1l, acc[1][1], 0, 0, 0);             \
        acc[0][0] = MFMA_BF16(a0l, b0h, acc[0][0], 0, 0, 0);             \
        acc[0][1] = MFMA_BF16(a0l, b1h, acc[0][1], 0, 0, 0);             \
        acc[1][0] = MFMA_BF16(a1l, b0h, acc[1][0], 0, 0, 0);             \
        acc[1][1] = MFMA_BF16(a1l, b1h, acc[1][1], 0, 0, 0);             \
    } while (0)

// ---------------------------------------------------------------------------
// Packed-tile position helper (R13): within a 16 KB (8192-short) tile
// covering 128 panel-rows x 64 k-cols, chunk (r, c) [r 0..127, c 0..7, 8 bf16]
// lives at shorts offset: half*4096 + j*512 + l*8, where
//   half = r>>6, rh = r&63, j = rh>>3, r8 = rh&7, l = (r8<<3) | (c ^ r8).
// This bakes the gemm's lane swizzle in, so gemm lanes read purely linearly:
// one gl_lds16 = one contiguous 1 KB segment (vs 8 scattered 128 B segments).
// ---------------------------------------------------------------------------
__device__ __forceinline__ int packed_off(int r, int c) {
    const int half = r >> 6;
    const int rh = r & 63;
    const int j = rh >> 3;
    const int r8 = rh & 7;
    const int l = (r8 << 3) | (c ^ r8);
    return half * 4096 + j * 512 + l * 8;
}

// ---------------------------------------------------------------------------
// convert_pack (R13): X -> packed Ahp/Alp tiles; W_enc -> packed Bhp/Blp
// tiles; W_fc -> Wth/Wtl (layout unchanged); zeroes labPack.
// grid 2096 x 256.
// ---------------------------------------------------------------------------
__global__ __launch_bounds__(256) void convert_pack(
    const float* __restrict__ img_q, const float* __restrict__ img_q1,
    const float* __restrict__ W_enc, const float* __restrict__ W_fc,
    short* __restrict__ Ahp, short* __restrict__ Alp,
    short* __restrict__ Bhp, short* __restrict__ Blp,
    short* __restrict__ Wth, short* __restrict__ Wtl,
    unsigned long long* __restrict__ labPack)
{
    __shared__ float tile[64][65];
    const int bid = blockIdx.x;
    const int t = threadIdx.x;

    if (bid < 4)
        labPack[bid * 256 + t] = 0ull;

    if (bid < 1024) {
        // X path: one 16 B chunk (8 cols) per thread-iteration.
        // 2048 rows x 1024 chunks = 2M chunks; 262144 threads x 8 iters.
        const int total = 2048 * 1024;
        for (int i = bid * 256 + t; i < total; i += 1024 * 256) {
            const int row = i >> 10;
            const int cc = i & 1023;
            const float* src = (row < B_SZ)
                ? &img_q[(size_t)row * D_SZ + cc * 8]
                : &img_q1[(size_t)(row - B_SZ) * D_SZ + cc * 8];
            float4 a = ((const float4*)src)[0];
            float4 b = ((const float4*)src)[1];
            float f[8] = {a.x, a.y, a.z, a.w, b.x, b.y, b.z, b.w};
            short8v h, l;
#pragma unroll
            for (int e = 0; e < 8; ++e) {
                short hh, ll;
                split_bf16(f[e], hh, ll);
                h[e] = hh; l[e] = ll;
            }
            const int mt = row >> 7;
            const int pr = row & 127;
            const int kstep = cc >> 3;
            const int c = cc & 7;
            const size_t dst = (size_t)(mt * 128 + kstep) * 8192 + packed_off(pr, c);
            *(short8v*)&Ahp[dst] = h;
            *(short8v*)&Alp[dst] = l;
        }
    } else if (bid < 2048) {
        // W_enc path: 64(k) x 64(n) tile transpose via LDS, emit packed chunks.
        const int id = bid - 1024;
        const int kstep = id >> 3;            // k0 = kstep*64
        const int k0 = kstep * 64;
        const int n0 = (id & 7) * 64;
        {
            const int kr = t >> 2;
            const int cb = (t & 3) * 16;
#pragma unroll
            for (int j = 0; j < 4; ++j) {
                float4 v = *(const float4*)&W_enc[(size_t)(k0 + kr) * F_SZ + n0 + cb + j * 4];
                tile[kr][cb + j * 4 + 0] = v.x;
                tile[kr][cb + j * 4 + 1] = v.y;
                tile[kr][cb + j * 4 + 2] = v.z;
                tile[kr][cb + j * 4 + 3] = v.w;
            }
        }
        __syncthreads();
        const int n = t >> 2;
#pragma unroll
        for (int cc2 = 0; cc2 < 2; ++cc2) {
            const int ch = (t & 3) * 2 + cc2;   // chunk c (0..7)
            short8v h, l;
#pragma unroll
            for (int e = 0; e < 8; ++e) {
                short hh, ll;
                split_bf16(tile[ch * 8 + e][n], hh, ll);
                h[e] = hh; l[e] = ll;
            }
            const int nrow = n0 + n;
            const int nt = nrow >> 7;
            const int pr = nrow & 127;
            const size_t dst = (size_t)(nt * 128 + kstep) * 8192 + packed_off(pr, ch);
            *(short8v*)&Bhp[dst] = h;
            *(short8v*)&Blp[dst] = l;
        }
    } else {
        // W_fc path: unchanged layout (Wth/Wtl [c][k])
        const int id = bid - 2048;
        const int k0 = (id & 7) * 64;
        const int c0 = (id >> 3) * 64;
        for (int idx = t; idx < 64 * 64; idx += 256) {
            const int kr = idx >> 6;
            const int cc = idx & 63;
            tile[kr][cc] = (c0 + cc < C_SZ) ? W_fc[(size_t)(k0 + kr) * C_SZ + c0 + cc] : 0.0f;
        }
        __syncthreads();
        const int crow = t >> 2;
#pragma unroll
        for (int cc2 = 0; cc2 < 2; ++cc2) {
            const int ch = (t & 3) * 2 + cc2;
            short8v h, l;
#pragma unroll
            for (int e = 0; e < 8; ++e) {
                short hh, ll;
                split_bf16(tile[ch * 8 + e][crow], hh, ll);
                h[e] = hh; l[e] = ll;
            }
            size_t off = (size_t)(c0 + crow) * F_SZ + k0 + ch * 8;
            *(short8v*)&Wth[off] = h;
            *(short8v*)&Wtl[off] = l;
        }
    }
}

// ---------------------------------------------------------------------------
// gemm_ws128_v4 (R13): identical schedule/LDS/numerics to v3 (512 thr, 8
// waves, dbuf, counted vmcnt(8), setprio, XCD swizzle) but staging reads the
// PACKED tiles: each gl_lds16 is one contiguous aligned 1 KB segment.
// grid (4,16,4) x 512 threads, ksteps=32.
// ---------------------------------------------------------------------------
__global__ __launch_bounds__(512, 1) void gemm_ws128_v4(
    const short* __restrict__ Ahp, const short* __restrict__ Alp,
    const short* __restrict__ Bhp, const short* __restrict__ Blp,
    float* __restrict__ P, int ksteps)
{
    __shared__ __align__(16) short sAh[2][8192];
    __shared__ __align__(16) short sAl[2][8192];
    __shared__ __align__(16) short sBh[2][8192];
    __shared__ __align__(16) short sBl[2][8192];

    const int t = threadIdx.x;
    const int lane = t & 63;
    const int wave = t >> 6;

    // XCD-aware bijective swizzle (flat id, nwg = 256)
    const int flat = blockIdx.x + 4 * blockIdx.y + 64 * blockIdx.z;
    const int logical = (flat & 7) * 32 + (flat >> 3);
    const int nt = logical & 3;
    const int mt = (logical >> 2) & 15;
    const int ks = logical >> 6;

    const int m0 = mt * 128;
    const int n0 = nt * 128;

    // staging role: arr = which LDS array, half = which 64 rows
    const int arr = wave >> 1;
    const int half = wave & 1;
    const short* gtile =
        (arr == 0) ? Ahp + (size_t)(mt * 128) * 8192 :
        (arr == 1) ? Alp + (size_t)(mt * 128) * 8192 :
        (arr == 2) ? Bhp + (size_t)(nt * 128) * 8192 :
                     Blp + (size_t)(nt * 128) * 8192;
    short* lb[2];
    lb[0] = ((arr == 0) ? sAh[0] : (arr == 1) ? sAl[0] : (arr == 2) ? sBh[0] : sBl[0]) + half * 4096;
    lb[1] = ((arr == 0) ? sAh[1] : (arr == 1) ? sAl[1] : (arr == 2) ? sBh[1] : sBl[1]) + half * 4096;
    // per-step source: gtile + (ks*32+s)*8192 + half*4096 + lane*8; j adds 512
    const short* gsrc0 = gtile + (size_t)(ks * ksteps) * 8192 + half * 4096 + lane * 8;

    // compute role: wave tile 64 rows x 32 cols
    const int wr = wave >> 2;
    const int wc = wave & 3;
    const int mo = wr * 64;
    const int no = wc * 32;
    const int lr = lane & 15;
    const int lkg = lane >> 4;
    const int x7 = lr & 7;
    const int sl0 = lkg ^ x7;
    const int sl1 = (4 + lkg) ^ x7;
    int aoff[4], boff[2];
#pragma unroll
    for (int f = 0; f < 4; ++f) aoff[f] = (mo + 16 * f + lr) * 64;
#pragma unroll
    for (int g = 0; g < 2; ++g) boff[g] = (no + 16 * g + lr) * 64;

    f32x4 acc[4][2] = {};

#pragma unroll
    for (int j = 0; j < 8; ++j)
        gl_lds16(gsrc0 + j * 512, lb[0] + j * 512);

    int buf = 0;
    for (int s = 0; s < ksteps; ++s) {
        if (s + 1 < ksteps) {
            short* dst = lb[buf ^ 1];
            const short* g = gsrc0 + (size_t)(s + 1) * 8192;
#pragma unroll
            for (int j = 0; j < 8; ++j)
                gl_lds16(g + j * 512, dst + j * 512);
            // drain only the current buffer's 8 loads; the 8 just issued for
            // buf^1 stay in flight across both MFMA phases (T4).
            asm volatile("s_waitcnt vmcnt(8)" ::: "memory");
        } else {
            asm volatile("s_waitcnt vmcnt(0)" ::: "memory");
        }
        fence_barrier();   // staged data visible to all waves

        const short* pAh = sAh[buf];
        const short* pAl = sAl[buf];
        const short* pBh = sBh[buf];
        const short* pBl = sBl[buf];

        // ---- phase 0 (ksub = 0) ----
        {
            bf16x8 ah[4], al[4], bh[2], bl_[2];
#pragma unroll
            for (int f = 0; f < 4; ++f) {
                ah[f] = *(const bf16x8*)&pAh[aoff[f] + sl0 * 8];
                al[f] = *(const bf16x8*)&pAl[aoff[f] + sl0 * 8];
            }
#pragma unroll
            for (int g = 0; g < 2; ++g) {
                bh[g]  = *(const bf16x8*)&pBh[boff[g] + sl0 * 8];
                bl_[g] = *(const bf16x8*)&pBl[boff[g] + sl0 * 8];
            }
            __builtin_amdgcn_s_setprio(1);
#pragma unroll
            for (int f = 0; f < 4; ++f)
#pragma unroll
                for (int g = 0; g < 2; ++g)
                    acc[f][g] = MFMA_BF16(ah[f], bh[g], acc[f][g], 0, 0, 0);
#pragma unroll
            for (int f = 0; f < 4; ++f)
#pragma unroll
                for (int g = 0; g < 2; ++g)
                    acc[f][g] = MFMA_BF16(ah[f], bl_[g], acc[f][g], 0, 0, 0);
#pragma unroll
            for (int f = 0; f < 4; ++f)
#pragma unroll
                for (int g = 0; g < 2; ++g)
                    acc[f][g] = MFMA_BF16(al[f], bh[g], acc[f][g], 0, 0, 0);
            __builtin_amdgcn_s_setprio(0);
        }
        fence_barrier();   // phase split: keeps waves role-interleaved

        // ---- phase 1 (ksub = 1) ----
        {
            bf16x8 ah[4], al[4], bh[2], bl_[2];
#pragma unroll
            for (int f = 0; f < 4; ++f) {
                ah[f] = *(const bf16x8*)&pAh[aoff[f] + sl1 * 8];
                al[f] = *(const bf16x8*)&pAl[aoff[f] + sl1 * 8];
            }
#pragma unroll
            for (int g = 0; g < 2; ++g) {
                bh[g]  = *(const bf16x8*)&pBh[boff[g] + sl1 * 8];
                bl_[g] = *(const bf16x8*)&pBl[boff[g] + sl1 * 8];
            }
            __builtin_amdgcn_s_setprio(1);
#pragma unroll
            for (int f = 0; f < 4; ++f)
#pragma unroll
                for (int g = 0; g < 2; ++g)
                    acc[f][g] = MFMA_BF16(ah[f], bh[g], acc[f][g], 0, 0, 0);
#pragma unroll
            for (int f = 0; f < 4; ++f)
#pragma unroll
                for (int g = 0; g < 2; ++g)
                    acc[f][g] = MFMA_BF16(ah[f], bl_[g], acc[f][g], 0, 0, 0);
#pragma unroll
            for (int f = 0; f < 4; ++f)
#pragma unroll
                for (int g = 0; g < 2; ++g)
                    acc[f][g] = MFMA_BF16(al[f], bh[g], acc[f][g], 0, 0, 0);
            __builtin_amdgcn_s_setprio(0);
        }
        fence_barrier();   // all reads of buf done before next overwrite
        buf ^= 1;
    }

    float* Pout = P + (size_t)ks * (2048u * 512u);
#pragma unroll
    for (int f = 0; f < 4; ++f)
#pragma unroll
        for (int g = 0; g < 2; ++g) {
            const int col  = n0 + no + 16 * g + (lane & 15);
            const int row0 = m0 + mo + 16 * f + (lane >> 4) * 4;
#pragma unroll
            for (int r = 0; r < 4; ++r)
                Pout[(size_t)(row0 + r) * F_SZ + col] = acc[f][g][r];
        }
}

// ---------------------------------------------------------------------------
// reduce_feats4: sum the 4 split-K P slices once -> feats fp32 + Fh/Fl
// bf16 split. Same summation order as before (bit-identical).
// ---------------------------------------------------------------------------
__global__ __launch_bounds__(256) void reduce_feats4(
    const float* __restrict__ P, float* __restrict__ feats,
    short* __restrict__ Fh, short* __restrict__ Fl)
{
    const int i4 = blockIdx.x * 256 + threadIdx.x;
    float4 a = ((const float4*)P)[i4];
#pragma unroll
    for (int sl = 1; sl < 4; ++sl) {
        float4 b = ((const float4*)(P + (size_t)sl * (2048u * 512u)))[i4];
        a.x += b.x; a.y += b.y; a.z += b.z; a.w += b.w;
    }
    ((float4*)feats)[i4] = a;
    float v[4] = {a.x, a.y, a.z, a.w};
    short4v h, l;
    short hh, ll;
#pragma unroll
    for (int e = 0; e < 4; ++e) {
        split_bf16(v[e], hh, ll); h[e] = hh; l[e] = ll;
    }
    ((short4v*)Fh)[i4] = h;
    ((short4v*)Fl)[i4] = l;
}

// ---------------------------------------------------------------------------
// fc_logits3: logits = feats @ W_fc^T + bias from bf16 Fh/Fl (L2-resident)
// with fused packed-atomicMax masked argmax. Double-buffered 64 KB LDS
// (2 blocks/CU), counted-vmcnt pipeline. grid (6,32).
// ---------------------------------------------------------------------------
__global__ __launch_bounds__(256, 2) void fc_logits3(
    const short* __restrict__ Ah, const short* __restrict__ Al,
    const short* __restrict__ Bh_g, const short* __restrict__ Bl_g,
    const float* __restrict__ bias, const float* __restrict__ partial_Y,
    float* __restrict__ logits, unsigned long long* __restrict__ labPack)
{
    __shared__ __align__(16) short dAh[2][4096];
    __shared__ __align__(16) short dAl[2][4096];
    __shared__ __align__(16) short dBh[2][4096];
    __shared__ __align__(16) short dBl[2][4096];

    const int t = threadIdx.x;
    const int lane = t & 63;
    const int wave = t >> 6;
    const int n0 = blockIdx.x * 64;
    const int m0 = blockIdx.y * 64;

    const int lrow8 = lane >> 3;
    const int colOff = ((lane & 7) ^ lrow8) * 8;

    const short* gsrc = (wave == 0) ? Ah : (wave == 1) ? Al
                      : (wave == 2) ? Bh_g : Bl_g;
    const int rbase = (wave < 2) ? m0 : n0;
    short* lb[2];
    lb[0] = (wave == 0) ? dAh[0] : (wave == 1) ? dAl[0] : (wave == 2) ? dBh[0] : dBl[0];
    lb[1] = (wave == 0) ? dAh[1] : (wave == 1) ? dAl[1] : (wave == 2) ? dBh[1] : dBl[1];
    const short* gbase = gsrc + (size_t)(rbase + lrow8) * F_SZ + colOff;

    const int mo = (wave >> 1) * 32;
    const int no = (wave & 1) * 32;
    const int lr = lane & 15;
    const int lkg = lane >> 4;
    const int x7 = lr & 7;
    const int sl0 = (0 + lkg) ^ x7;
    const int sl1 = (4 + lkg) ^ x7;
    const int ra0 = (mo + lr) * 64,      ra1 = (mo + 16 + lr) * 64;
    const int rb0 = (no + lr) * 64,      rb1 = (no + 16 + lr) * 64;
    const int a00 = ra0 + sl0 * 8, a01 = ra0 + sl1 * 8;
    const int a10 = ra1 + sl0 * 8, a11 = ra1 + sl1 * 8;
    const int b00 = rb0 + sl0 * 8, b01 = rb0 + sl1 * 8;
    const int b10 = rb1 + sl0 * 8, b11 = rb1 + sl1 * 8;

    f32x4 acc[2][2] = {};

#pragma unroll
    for (int j = 0; j < 8; ++j)
        gl_lds16(gbase + (size_t)(8 * j) * F_SZ, lb[0] + j * 512);

    int buf = 0;
    for (int s = 0; s < 8; ++s) {
        if (s + 1 < 8) {
            short* dst = lb[buf ^ 1];
            const short* g = gbase + (s + 1) * 64;
#pragma unroll
            for (int j = 0; j < 8; ++j)
                gl_lds16(g + (size_t)(8 * j) * F_SZ, dst + j * 512);
            asm volatile("s_waitcnt vmcnt(8)" ::: "memory");
        } else {
            asm volatile("s_waitcnt vmcnt(0)" ::: "memory");
        }
        fence_barrier();
        __builtin_amdgcn_s_setprio(1);
        {
            const short* sAh = dAh[buf];
            const short* sAl = dAl[buf];
            const short* sBh = dBh[buf];
            const short* sBl = dBl[buf];
            MFMA_BLOCK(a00, a10, b00, b10);
            MFMA_BLOCK(a01, a11, b01, b11);
        }
        __builtin_amdgcn_s_setprio(0);
        fence_barrier();
        buf ^= 1;
    }

    const bool doArg = (m0 < B_SZ);
#pragma unroll
    for (int f = 0; f < 2; ++f) {
#pragma unroll
        for (int r = 0; r < 4; ++r) {
            const int row = m0 + mo + f * 16 + (lane >> 4) * 4 + r;
            unsigned long long best = 0;
#pragma unroll
            for (int g = 0; g < 2; ++g) {
                const int col = n0 + no + g * 16 + (lane & 15);
                if (col < C_SZ) {
                    const float v = acc[f][g][r] + bias[col];
                    logits[(size_t)row * C_SZ + col] = v;
                    if (doArg && partial_Y[(size_t)row * C_SZ + col] != 0.0f) {
                        unsigned long long p = ((unsigned long long)f2key(v) << 32)
                                             | (unsigned long long)(0xFFFFFFFFu - (unsigned)col);
                        if (p > best) best = p;
                    }
                }
            }
            if (doArg) {
#pragma unroll
                for (int m = 1; m < 16; m <<= 1) {
                    unsigned long long o = __shfl_xor(best, m);
                    if (o > best) best = o;
                }
                if ((lane & 15) == 0 && best != 0)
                    atomicMax(&labPack[row], best);
            }
        }
    }
}

// ---------------------------------------------------------------------------
// proto_scores_fused: per class c —
//   phase 1 (wave 0): ballot-decode labPack into ordered rowlist
//   phase 2: EMA over matching rows (order preserved), L2 renorm, write proto
//   phase 3: scores row, coalesced; shuffle-reduce. grid 345, 512 threads.
// ---------------------------------------------------------------------------
__global__ __launch_bounds__(512) void proto_scores_fused(
    const unsigned long long* __restrict__ labPack,
    const float* __restrict__ feats_q,
    const float* __restrict__ proto,
    const short* __restrict__ Wth, const short* __restrict__ Wtl,
    const float* __restrict__ b_fc,
    float* __restrict__ new_proto, float* __restrict__ scores,
    float* __restrict__ labels_f)
{
    __shared__ int rowlist[B_SZ];
    __shared__ int mcount_s;
    __shared__ float nprow[F_SZ];
    __shared__ float red[8];
    __shared__ float rinv_s;
    const int c = blockIdx.x;
    const int t = threadIdx.x;
    const int lane = t & 63;
    const int w = t >> 6;

    if (c == 0) {
#pragma unroll
        for (int j = 0; j < 2; ++j) {
            const int i = t + j * 512;
            int li = (int)(0xFFFFFFFFu - (unsigned)(labPack[i] & 0xFFFFFFFFull));
            labels_f[i] = (float)li;
        }
    }

    if (w == 0) {
        int k = 0;
#pragma unroll
        for (int ch = 0; ch < 16; ++ch) {
            unsigned long long pk = labPack[ch * 64 + lane];
            int li = (int)(0xFFFFFFFFu - (unsigned)(pk & 0xFFFFFFFFull));
            unsigned long long mask = __ballot(li == c);
            if (lane == 0) {
                while (mask) {
                    int p = __builtin_ctzll(mask);
                    mask &= mask - 1;
                    rowlist[k++] = ch * 64 + p;
                }
            }
            k = __shfl(k, 0);
        }
        if (lane == 0) mcount_s = k;
    }
    __syncthreads();
    const int m = mcount_s;

    float val = proto[(size_t)c * F_SZ + t];
    for (int k = 0; k < m; ++k)
        val = PROTO_W * val + (1.0f - PROTO_W) * feats_q[(size_t)rowlist[k] * F_SZ + t];

    float sq = val * val;
#pragma unroll
    for (int off = 32; off; off >>= 1) sq += __shfl_down(sq, off);
    if ((t & 63) == 0) red[t >> 6] = sq;
    __syncthreads();
    if (t == 0) {
        float s = 0.0f;
#pragma unroll
        for (int ww = 0; ww < 8; ++ww) s += red[ww];
        rinv_s = 1.0f / sqrtf(s);
    }
    __syncthreads();
    const float v = val * rinv_s;
    new_proto[(size_t)c * F_SZ + t] = v;
    nprow[t] = v;
    __syncthreads();

    float np8[8];
#pragma unroll
    for (int j = 0; j < 8; ++j) np8[j] = nprow[lane * 8 + j];
    for (int col = w; col < C_SZ; col += 8) {
        const short8v h = *(const short8v*)&Wth[(size_t)col * F_SZ + lane * 8];
        const short8v l = *(const short8v*)&Wtl[(size_t)col * F_SZ + lane * 8];
        float p = 0.0f;
#pragma unroll
        for (int j = 0; j < 8; ++j)
            p += np8[j] * (bf16_f32(h[j]) + bf16_f32(l[j]));
#pragma unroll
        for (int off = 32; off; off >>= 1) p += __shfl_down(p, off);
        if (lane == 0) scores[(size_t)c * C_SZ + col] = p + b_fc[col];
    }
}

// ===========================================================================
// OLD-path kernels (R6-proven fallback; used when ws < WS2_NEED)
// ===========================================================================
__global__ __launch_bounds__(256) void convert_all(
    const float* __restrict__ img_q, const float* __restrict__ img_q1,
    const float* __restrict__ W_enc, const float* __restrict__ W_fc,
    short* __restrict__ Xh, short* __restrict__ Xl,
    short* __restrict__ Wh, short* __restrict__ Wl,
    short* __restrict__ Wth, short* __restrict__ Wtl,
    unsigned long long* __restrict__ labPack)
{
    __shared__ float tile[64][65];
    const int bid = blockIdx.x;
    const int t = threadIdx.x;

    if (labPack && bid < 4)
        labPack[bid * 256 + t] = 0ull;

    if (bid < 1024) {
        const int HALF = (B_SZ * D_SZ) / 4;
        const int total = 2 * HALF;
        for (int i4 = bid * 256 + t; i4 < total; i4 += 1024 * 256) {
            float4 v = (i4 < HALF) ? ((const float4*)img_q)[i4]
                                   : ((const float4*)img_q1)[i4 - HALF];
            short4v h, l;
            short hh, ll;
            split_bf16(v.x, hh, ll); h.x = hh; l.x = ll;
            split_bf16(v.y, hh, ll); h.y = hh; l.y = ll;
            split_bf16(v.z, hh, ll); h.z = hh; l.z = ll;
            split_bf16(v.w, hh, ll); h.w = hh; l.w = ll;
            ((short4v*)Xh)[i4] = h;
            ((short4v*)Xl)[i4] = l;
        }
    } else if (bid < 2048) {
        const int id = bid - 1024;
        const int k0 = (id >> 3) * 64;
        const int n0 = (id & 7) * 64;
        {
            const int kr = t >> 2;
            const int cb = (t & 3) * 16;
#pragma unroll
            for (int j = 0; j < 4; ++j) {
                float4 v = *(const float4*)&W_enc[(size_t)(k0 + kr) * F_SZ + n0 + cb + j * 4];
                tile[kr][cb + j * 4 + 0] = v.x;
                tile[kr][cb + j * 4 + 1] = v.y;
                tile[kr][cb + j * 4 + 2] = v.z;
                tile[kr][cb + j * 4 + 3] = v.w;
            }
        }
        __syncthreads();
        const int n = t >> 2;
#pragma unroll
        for (int cc = 0; cc < 2; ++cc) {
            const int ch = (t & 3) * 2 + cc;
            short8v h, l;
#pragma unroll
            for (int e = 0; e < 8; ++e) {
                short hh, ll;
                split_bf16(tile[ch * 8 + e][n], hh, ll);
                h[e] = hh; l[e] = ll;
            }
            size_t off = (size_t)(n0 + n) * D_SZ + k0 + ch * 8;
            *(short8v*)&Wh[off] = h;
            *(short8v*)&Wl[off] = l;
        }
    } else {
        const int id = bid - 2048;
        const int k0 = (id & 7) * 64;
        const int c0 = (id >> 3) * 64;
        for (int idx = t; idx < 64 * 64; idx += 256) {
            const int kr = idx >> 6;
            const int cc = idx & 63;
            tile[kr][cc] = (c0 + cc < C_SZ) ? W_fc[(size_t)(k0 + kr) * C_SZ + c0 + cc] : 0.0f;
        }
        __syncthreads();
        const int crow = t >> 2;
#pragma unroll
        for (int cc2 = 0; cc2 < 2; ++cc2) {
            const int ch = (t & 3) * 2 + cc2;
            short8v h, l;
#pragma unroll
            for (int e = 0; e < 8; ++e) {
                short hh, ll;
                split_bf16(tile[ch * 8 + e][crow], hh, ll);
                h[e] = hh; l[e] = ll;
            }
            size_t off = (size_t)(c0 + crow) * F_SZ + k0 + ch * 8;
            *(short8v*)&Wth[off] = h;
            *(short8v*)&Wtl[off] = l;
        }
    }
}

__global__ __launch_bounds__(256, 1) void gemm_ws128(
    const short* __restrict__ Xh, const short* __restrict__ Xl,
    const short* __restrict__ Wh, const short* __restrict__ Wl,
    float* __restrict__ P, int ksteps)
{
    __shared__ __align__(16) short sAh[2][8192];
    __shared__ __align__(16) short sAl[2][8192];
    __shared__ __align__(16) short sBh[2][8192];
    __shared__ __align__(16) short sBl[2][8192];

    const int t = threadIdx.x;
    const int lane = t & 63;
    const int wave = t >> 6;
    const int nt = blockIdx.x;
    const int mt = blockIdx.y;
    const int ks = blockIdx.z;
    const int m0 = mt * 128;
    const int n0 = nt * 128;
    const int kbase = ks * ksteps * 64;

    const short* gbase =
        (wave == 0) ? Xh + (size_t)m0 * D_SZ :
        (wave == 1) ? Xl + (size_t)m0 * D_SZ :
        (wave == 2) ? Wh + (size_t)n0 * D_SZ :
                      Wl + (size_t)n0 * D_SZ;
    short* lb[2];
    lb[0] = (wave == 0) ? sAh[0] : (wave == 1) ? sAl[0] : (wave == 2) ? sBh[0] : sBl[0];
    lb[1] = (wave == 0) ? sAh[1] : (wave == 1) ? sAl[1] : (wave == 2) ? sBh[1] : sBl[1];
    const int lrow8 = lane >> 3;
    const int gchunkOff = ((lane & 7) ^ lrow8) * 8;
    const short* gsrc = gbase + (size_t)lrow8 * D_SZ + kbase + gchunkOff;

    const int mo = (wave >> 1) * 64;
    const int no = (wave & 1) * 64;
    const int lr = lane & 15;
    const int lkg = lane >> 4;
    const int x7 = lr & 7;
    const int sl0 = lkg ^ x7;
    const int sl1 = (4 + lkg) ^ x7;
    int aoff[4], boff[4];
#pragma unroll
    for (int f = 0; f < 4; ++f) {
        aoff[f] = (mo + 16 * f + lr) * 64;
        boff[f] = (no + 16 * f + lr) * 64;
    }

    f32x4 acc[4][4] = {};

#pragma unroll
    for (int j = 0; j < 16; ++j)
        gl_lds16(gsrc + (size_t)(8 * j) * D_SZ, lb[0] + j * 512);

    int buf = 0;
    for (int s = 0; s < ksteps; ++s) {
        if (s + 1 < ksteps) {
            short* dst = lb[buf ^ 1];
            const short* g = gsrc + (s + 1) * 64;
#pragma unroll
            for (int j = 0; j < 16; ++j)
                gl_lds16(g + (size_t)(8 * j) * D_SZ, dst + j * 512);
            asm volatile("s_waitcnt vmcnt(16)" ::: "memory");
        } else {
            asm volatile("s_waitcnt vmcnt(0)" ::: "memory");
        }
        fence_barrier();

        __builtin_amdgcn_s_setprio(1);
        {
            const short* pAh = sAh[buf];
            const short* pAl = sAl[buf];
            const short* pBh = sBh[buf];
            const short* pBl = sBl[buf];
#pragma unroll
            for (int ksub = 0; ksub < 2; ++ksub) {
                const int sl = ksub ? sl1 : sl0;
                bf16x8 ah[4], al[4], bh[4], blo[4];
#pragma unroll
                for (int f = 0; f < 4; ++f) {
                    ah[f]  = *(const bf16x8*)&pAh[aoff[f] + sl * 8];
                    al[f]  = *(const bf16x8*)&pAl[aoff[f] + sl * 8];
                }
#pragma unroll
                for (int g = 0; g < 4; ++g) {
                    bh[g]  = *(const bf16x8*)&pBh[boff[g] + sl * 8];
                    blo[g] = *(const bf16x8*)&pBl[boff[g] + sl * 8];
                }
#pragma unroll
                for (int f = 0; f < 4; ++f)
#pragma unroll
                    for (int g = 0; g < 4; ++g)
                        acc[f][g] = MFMA_BF16(ah[f], bh[g], acc[f][g], 0, 0, 0);
#pragma unroll
                for (int f = 0; f < 4; ++f)
#pragma unroll
                    for (int g = 0; g < 4; ++g)
                        acc[f][g] = MFMA_BF16(ah[f], blo[g], acc[f][g], 0, 0, 0);
#pragma unroll
                for (int f = 0; f < 4; ++f)
#pragma unroll
                    for (int g = 0; g < 4; ++g)
                        acc[f][g] = MFMA_BF16(al[f], bh[g], acc[f][g], 0, 0, 0);
            }
        }
        __builtin_amdgcn_s_setprio(0);
        fence_barrier();
        buf ^= 1;
    }

    float* Pout = P + (size_t)ks * (2048u * 512u);
#pragma unroll
    for (int f = 0; f < 4; ++f)
#pragma unroll
        for (int g = 0; g < 4; ++g) {
            const int col  = n0 + no + 16 * g + (lane & 15);
            const int row0 = m0 + mo + 16 * f + (lane >> 4) * 4;
#pragma unroll
            for (int r = 0; r < 4; ++r)
                Pout[(size_t)(row0 + r) * F_SZ + col] = acc[f][g][r];
        }
}

__global__ __launch_bounds__(256) void reduce_feats_split(
    const float* __restrict__ P, float* __restrict__ feats,
    short* __restrict__ Fh, short* __restrict__ Fl,
    const float* __restrict__ W_fc,
    short* __restrict__ Wth, short* __restrict__ Wtl)
{
    const int bid = blockIdx.x;
    const int t = threadIdx.x;
    if (bid < 1024) {
        const int n4 = (2048 * 512) / 4;
        const float* P1 = P + 2048 * 512;
        for (int i4 = bid * 256 + t; i4 < n4; i4 += 1024 * 256) {
            float4 a = ((const float4*)P)[i4];
            float4 b = ((const float4*)P1)[i4];
            float v[4] = {a.x + b.x, a.y + b.y, a.z + b.z, a.w + b.w};
            short4v h, l;
            short hh, ll;
#pragma unroll
            for (int e = 0; e < 4; ++e) {
                feats[i4 * 4 + e] = v[e];
                split_bf16(v[e], hh, ll); h[e] = hh; l[e] = ll;
            }
            ((short4v*)Fh)[i4] = h;
            ((short4v*)Fl)[i4] = l;
        }
    } else {
        __shared__ float tile[64][65];
        const int id = bid - 1024;
        const int k0 = (id & 7) * 64;
        const int c0 = (id >> 3) * 64;
        for (int idx = t; idx < 64 * 64; idx += 256) {
            const int kr = idx >> 6;
            const int cc = idx & 63;
            tile[kr][cc] = (c0 + cc < C_SZ) ? W_fc[(size_t)(k0 + kr) * C_SZ + c0 + cc] : 0.0f;
        }
        __syncthreads();
        const int crow = t >> 2;
#pragma unroll
        for (int cc2 = 0; cc2 < 2; ++cc2) {
            const int ch = (t & 3) * 2 + cc2;
            short8v h, l;
#pragma unroll
            for (int e = 0; e < 8; ++e) {
                short hh, ll;
                split_bf16(tile[ch * 8 + e][crow], hh, ll);
                h[e] = hh; l[e] = ll;
            }
            size_t off = (size_t)(c0 + crow) * F_SZ + k0 + ch * 8;
            *(short8v*)&Wth[off] = h;
            *(short8v*)&Wtl[off] = l;
        }
    }
}

__global__ __launch_bounds__(256) void gemm_fc(
    const short* __restrict__ Ah, const short* __restrict__ Al,
    const short* __restrict__ Bh, const short* __restrict__ Bl,
    const float* __restrict__ bias, float* __restrict__ Cout, int M)
{
    __shared__ __align__(16) short sAh[4096];
    __shared__ __align__(16) short sAl[4096];
    __shared__ __align__(16) short sBh[4096];
    __shared__ __align__(16) short sBl[4096];

    const int t = threadIdx.x;
    const int lane = t & 63;
    const int wave = t >> 6;
    const int n0 = blockIdx.x * 64;
    const int m0 = blockIdx.y * 64;

    const int lrow8 = lane >> 3;
    const int colOff = ((lane & 7) ^ lrow8) * 8;

    short* lbase = (wave == 0) ? sAh : (wave == 1) ? sAl : (wave == 2) ? sBh : sBl;
    const short* gA = (wave == 1) ? Al : Ah;
    const short* gB = (wave == 3) ? Bl : Bh;
    const bool isA = wave < 2;

    const int mo = (wave >> 1) * 32;
    const int no = (wave & 1) * 32;
    const int lr = lane & 15;
    const int lkg = lane >> 4;
    const int x7 = lr & 7;
    const int sl0 = (0 + lkg) ^ x7;
    const int sl1 = (4 + lkg) ^ x7;
    const int ra0 = (mo + lr) * 64,      ra1 = (mo + 16 + lr) * 64;
    const int rb0 = (no + lr) * 64,      rb1 = (no + 16 + lr) * 64;
    const int a00 = ra0 + sl0 * 8, a01 = ra0 + sl1 * 8;
    const int a10 = ra1 + sl0 * 8, a11 = ra1 + sl1 * 8;
    const int b00 = rb0 + sl0 * 8, b01 = rb0 + sl1 * 8;
    const int b10 = rb1 + sl0 * 8, b11 = rb1 + sl1 * 8;

    f32x4 acc[2][2] = {};

    for (int s = 0; s < 8; ++s) {
        __syncthreads();
        if (isA) {
#pragma unroll
            for (int j = 0; j < 8; ++j) {
                int row = m0 + lrow8 + 8 * j;
                if (row > M - 1) row = M - 1;
                gl_lds16(gA + (size_t)row * F_SZ + s * 64 + colOff, lbase + j * 512);
            }
        } else {
#pragma unroll
            for (int j = 0; j < 8; ++j) {
                int row = n0 + lrow8 + 8 * j;
                gl_lds16(gB + (size_t)row * F_SZ + s * 64 + colOff, lbase + j * 512);
            }
        }
        __syncthreads();
        MFMA_BLOCK(a00, a10, b00, b10);
        MFMA_BLOCK(a01, a11, b01, b11);
    }

#pragma unroll
    for (int f = 0; f < 2; ++f)
#pragma unroll
        for (int g = 0; g < 2; ++g) {
            const int col  = n0 + no + g * 16 + (lane & 15);
            if (col >= C_SZ) continue;
            const float bb = bias[col];
            const int row0 = m0 + mo + f * 16 + (lane >> 4) * 4;
#pragma unroll
            for (int r = 0; r < 4; ++r) {
                const int row = row0 + r;
                if (row < M)
                    Cout[(size_t)row * C_SZ + col] = acc[f][g][r] + bb;
            }
        }
}

__global__ __launch_bounds__(64) void argmax_labels(
    const float* __restrict__ logits, const float* __restrict__ partial_Y,
    float* __restrict__ labels_f)
{
    const int i = blockIdx.x;
    const int lane = threadIdx.x;
    float best = -FLT_MAX;
    int bidx = C_SZ;
    for (int c = lane; c < C_SZ; c += 64) {
        if (partial_Y[(size_t)i * C_SZ + c] != 0.0f) {
            float v = logits[(size_t)i * C_SZ + c];
            if (v > best || (v == best && c < bidx)) { best = v; bidx = c; }
        }
    }
#pragma unroll
    for (int off = 32; off; off >>= 1) {
        float ov = __shfl_down(best, off);
        int oi = __shfl_down(bidx, off);
        if (ov > best || (ov == best && oi < bidx)) { best = ov; bidx = oi; }
    }
    if (lane == 0) labels_f[i] = (float)bidx;
}

__global__ __launch_bounds__(512) void proto_update(
    const float* __restrict__ labels_f, const float* __restrict__ feats_q,
    const float* __restrict__ proto, float* __restrict__ new_proto,
    short* __restrict__ NPh, short* __restrict__ NPl)
{
    __shared__ int lab[B_SZ];
    __shared__ float red[8];
    __shared__ float rinv_s;
    const int c = blockIdx.x;
    const int t = threadIdx.x;
    for (int i = t; i < B_SZ; i += 512) lab[i] = (int)labels_f[i];
    __syncthreads();
    float val = proto[(size_t)c * F_SZ + t];
    for (int i = 0; i < B_SZ; ++i) {
        if (lab[i] == c)
            val = PROTO_W * val + (1.0f - PROTO_W) * feats_q[(size_t)i * F_SZ + t];
    }
    float sq = val * val;
#pragma unroll
    for (int off = 32; off; off >>= 1) sq += __shfl_down(sq, off);
    if ((t & 63) == 0) red[t >> 6] = sq;
    __syncthreads();
    if (t == 0) {
        float s = 0.0f;
#pragma unroll
        for (int w = 0; w < 8; ++w) s += red[w];
        rinv_s = 1.0f / sqrtf(s);
    }
    __syncthreads();
    const float v = val * rinv_s;
    new_proto[(size_t)c * F_SZ + t] = v;
    if (NPh) {
        short hh, ll;
        split_bf16(v, hh, ll);
        NPh[(size_t)c * F_SZ + t] = hh;
        NPl[(size_t)c * F_SZ + t] = ll;
    }
}

// ---------------------------------------------------------------------------
extern "C" void kernel_launch(void* const* d_in, const int* in_sizes, int n_in,
                              void* d_out, int out_size, void* d_ws, size_t ws_size,
                              hipStream_t stream)
{
    const float* img_q     = (const float*)d_in[0];
    const float* img_q1    = (const float*)d_in[1];
    const float* partial_Y = (const float*)d_in[2];
    const float* W_enc     = (const float*)d_in[3];
    const float* W_fc      = (const float*)d_in[4];
    const float* b_fc      = (const float*)d_in[5];
    const float* proto     = (const float*)d_in[6];

    float* out       = (float*)d_out;
    float* logits    = out;            // [2048][345]
    float* new_proto = out + 706560;   // [345][512]
    float* scores    = out + 883200;   // [345][345]
    float* labels_f  = out + 1002225;  // [1024]
    float* feats     = out + 1003249;  // [2048][512]

    char* ws = (char*)d_ws;
    short* Xh = (short*)(ws + WS_XH);
    short* Xl = (short*)(ws + WS_XL);
    short* Wh = (short*)(ws + WS_WH);
    short* Wl = (short*)(ws + WS_WL);
    float* P  = (float*)(ws + WS_P);

    if (ws_size >= (size_t)WS2_NEED) {
        short* Wth = (short*)(ws + WS2_WFH);
        short* Wtl = (short*)(ws + WS2_WFL);
        unsigned long long* labPack = (unsigned long long*)(ws + WS2_LAB);
        // Fh/Fl overlay Xh (dead after gemm; same-stream ordering)
        short* Fh = (short*)(ws + 0u);
        short* Fl = (short*)(ws + 2097152u);

        hipLaunchKernelGGL(convert_pack, dim3(2096), dim3(256), 0, stream,
                           img_q, img_q1, W_enc, W_fc, Xh, Xl, Wh, Wl, Wth, Wtl,
                           labPack);
        hipLaunchKernelGGL(gemm_ws128_v4, dim3(4, 16, 4), dim3(512), 0, stream,
                           Xh, Xl, Wh, Wl, P, 32);
        hipLaunchKernelGGL(reduce_feats4, dim3(1024), dim3(256), 0, stream,
                           P, feats, Fh, Fl);
        hipLaunchKernelGGL(fc_logits3, dim3(6, 32), dim3(256), 0, stream,
                           Fh, Fl, Wth, Wtl, b_fc, partial_Y, logits, labPack);
        hipLaunchKernelGGL(proto_scores_fused, dim3(345), dim3(512), 0, stream,
                           labPack, feats, proto, Wth, Wtl, b_fc,
                           new_proto, scores, labels_f);
    } else {
        short* Fh  = (short*)(ws + WS_FH);
        short* Fl  = (short*)(ws + WS_FL);
        short* Wth = (short*)(ws + WS_WFH);
        short* Wtl = (short*)(ws + WS_WFL);
        short* NPh = (short*)(ws + WS_NPH);
        short* NPl = (short*)(ws + WS_NPL);

        hipLaunchKernelGGL(convert_all, dim3(2048), dim3(256), 0, stream,
                           img_q, img_q1, W_enc, W_fc, Xh, Xl, Wh, Wl,
                           (short*)nullptr, (short*)nullptr,
                           (unsigned long long*)nullptr);
        hipLaunchKernelGGL(gemm_ws128, dim3(4, 16, 2), dim3(256), 0, stream,
                           Xh, Xl, Wh, Wl, P, 64);
        hipLaunchKernelGGL(reduce_feats_split, dim3(1072), dim3(256), 0, stream,
                           P, feats, Fh, Fl, W_fc, Wth, Wtl);
        hipLaunchKernelGGL(gemm_fc, dim3(6, 32), dim3(256), 0, stream,
                           Fh, Fl, Wth, Wtl, b_fc, logits, 2048);
        hipLaunchKernelGGL(argmax_labels, dim3(1024), dim3(64), 0, stream,
                           logits, partial_Y, labels_f);
        hipLaunchKernelGGL(proto_update, dim3(345), dim3(512), 0, stream,
                           labels_f, feats, proto, new_proto, NPh, NPl);
        hipLaunchKernelGGL(gemm_fc, dim3(6, 6), dim3(256), 0, stream,
                           NPh, NPl, Wth, Wtl, b_fc, scores, C_SZ);
    }
}

// Round 6
// 242.642 us; speedup vs baseline: 2.5320x; 1.0438x over previous
//
#include <hip/hip_runtime.h>
#include <float.h>
#include <math.h>

// Problem constants
#define B_SZ 1024
#define D_SZ 8192
#define C_SZ 345
#define F_SZ 512
#define PROTO_W 0.99f

// d_out layout (float32, flat, reference return order):
//   logits   [2048][345]  @ 0
//   new_proto[345][512]   @ 706560
//   scores   [345][345]   @ 883200
//   labels   [1024]       @ 1002225  (stored as float)
//   feats    [2048][512]  @ 1003249

// ---------------- NEW-path d_ws layout -----------
// R14: Xh/Xl hold packed A tiles [mt 0..15][kstep32 0..255][4096 shorts];
// Wh/Wl packed B tiles [nt 0..3][kstep32 0..255][4096 shorts].
#define WS_XH 0
#define WS_XL 33554432u
#define WS_WH 67108864u
#define WS_WL 75497472u
#define WS_P  83886080u
#define WS2_WFH 100663296u
#define WS2_WFL 101056512u
#define WS2_LAB 101449728u
#define WS2_NEED 101457920u

// ---------------- OLD-path (R6 fallback) overlay offsets ---------------------
#define WS_NEED 92274688u
#define WS_FH  0u
#define WS_FL  2097152u
#define WS_WFH 4194304u
#define WS_WFL 4587520u
#define WS_NPH 4980736u
#define WS_NPL 5373952u

typedef short bf16x8 __attribute__((ext_vector_type(8)));
typedef short short4v __attribute__((ext_vector_type(4)));
typedef short short8v __attribute__((ext_vector_type(8)));
typedef float f32x4  __attribute__((ext_vector_type(4)));

__device__ __forceinline__ void split_bf16(float x, short& hi, short& lo) {
    unsigned u = __float_as_uint(x);
    unsigned r = (u + 0x7FFFu + ((u >> 16) & 1u)) >> 16;
    hi = (short)r;
    float hf = __uint_as_float(r << 16);
    lo = (short)(__float_as_uint(x - hf) >> 16);
}
__device__ __forceinline__ float bf16_f32(short h) {
    return __uint_as_float(((unsigned)(unsigned short)h) << 16);
}

__device__ __forceinline__ void gl_lds16(const short* g, short* l) {
    __builtin_amdgcn_global_load_lds(
        (const __attribute__((address_space(1))) void*)g,
        (__attribute__((address_space(3))) void*)l, 16, 0, 0);
}

// order-preserving float -> u32 key (larger float => larger key)
__device__ __forceinline__ unsigned f2key(float v) {
    unsigned u = __float_as_uint(v);
    return (u & 0x80000000u) ? ~u : (u | 0x80000000u);
}

// Raw barrier with compiler memory fence but NO hardware counter drain.
__device__ __forceinline__ void fence_barrier() {
    asm volatile("" ::: "memory");
    __builtin_amdgcn_s_barrier();
    asm volatile("" ::: "memory");
}

#define MFMA_BF16 __builtin_amdgcn_mfma_f32_16x16x32_bf16

// 12-MFMA bf16x3 block (2x2 frags); expects sAh/sAl/sBh/sBl + acc in scope.
#define MFMA_BLOCK(IA0, IA1, IB0, IB1)                                   \
    do {                                                                 \
        bf16x8 a0h = *(const bf16x8*)&sAh[IA0];                          \
        bf16x8 a1h = *(const bf16x8*)&sAh[IA1];                          \
        bf16x8 b0h = *(const bf16x8*)&sBh[IB0];                          \
        bf16x8 b1h = *(const bf16x8*)&sBh[IB1];                          \
        bf16x8 a0l = *(const bf16x8*)&sAl[IA0];                          \
        bf16x8 a1l = *(const bf16x8*)&sAl[IA1];                          \
        bf16x8 b0l = *(const bf16x8*)&sBl[IB0];                          \
        bf16x8 b1l = *(const bf16x8*)&sBl[IB1];                          \
        acc[0][0] = MFMA_BF16(a0h, b0h, acc[0][0], 0, 0, 0);             \
        acc[0][1] = MFMA_BF16(a0h, b1h, acc[0][1], 0, 0, 0);             \
        acc[1][0] = MFMA_BF16(a1h, b0h, acc[1][0], 0, 0, 0);             \
        acc[1][1] = MFMA_BF16(a1h, b1h, acc[1][1], 0, 0, 0);             \
        acc[0][0] = MFMA_BF16(a0h, b0l, acc[0][0], 0, 0, 0);             \
        acc[0][1] = MFMA_BF16(a0h, b1l, acc[0][1], 0, 0, 0);             \
        acc[1][0] = MFMA_BF16(a1h, b0l, acc[1][0], 0, 0, 0);             \
        acc[1][1] = MFMA_BF16(a1h, b1l, acc[1][1], 0, 0, 0);             \
        acc[0][0] = MFMA_BF16(a0l, b0h, acc[0][0], 0, 0, 0);             \
        acc[0][1] = MFMA_BF16(a0l, b1h, acc[0][1], 0, 0, 0);             \
        acc[1][0] = MFMA_BF16(a1l, b0h, acc[1][0], 0, 0, 0);             \
        acc[1][1] = MFMA_BF16(a1l, b1h, acc[1][1], 0, 0, 0);             \
    } while (0)

// ---------------------------------------------------------------------------
// R14 packed layout: per (128-row-group, 32-k) tile = 4096 shorts.
// Element (pr 0..127, k 0..31): half = pr>>6, r = pr&63, rp = r>>1, p = r&1,
// c = k>>3, slot = ((p<<2)|c) ^ (rp&7):
//   off = half*2048 + rp*64 + slot*8 + (k&7)
// ds_read frag (row R, k-group lkg) reads bf16x8 at off(R, c=lkg) — bank
// pattern identical to the proven v3 swizzle (rp-stride 128 B, slot XOR).
// gl_lds staging is pure linear: lane*8 within each 512-short quarter.
// ---------------------------------------------------------------------------

// ---------------------------------------------------------------------------
// convert_pack2 (R14): X -> packed A tiles; W_enc -> packed B tiles;
// W_fc -> Wth/Wtl (unchanged layout); zeroes labPack. grid 2096 x 256.
// ---------------------------------------------------------------------------
__global__ __launch_bounds__(256) void convert_pack2(
    const float* __restrict__ img_q, const float* __restrict__ img_q1,
    const float* __restrict__ W_enc, const float* __restrict__ W_fc,
    short* __restrict__ Ahp, short* __restrict__ Alp,
    short* __restrict__ Bhp, short* __restrict__ Blp,
    short* __restrict__ Wth, short* __restrict__ Wtl,
    unsigned long long* __restrict__ labPack)
{
    __shared__ float tile[64][65];
    const int bid = blockIdx.x;
    const int t = threadIdx.x;

    if (bid < 4)
        labPack[bid * 256 + t] = 0ull;

    if (bid < 1024) {
        // X path: one 16 B chunk (8 k) per thread-iteration.
        const int total = 2048 * 1024;
        for (int i = bid * 256 + t; i < total; i += 1024 * 256) {
            const int row = i >> 10;
            const int cc = i & 1023;          // 8-k chunk index
            const float* src = (row < B_SZ)
                ? &img_q[(size_t)row * D_SZ + cc * 8]
                : &img_q1[(size_t)(row - B_SZ) * D_SZ + cc * 8];
            float4 a = ((const float4*)src)[0];
            float4 b = ((const float4*)src)[1];
            float f[8] = {a.x, a.y, a.z, a.w, b.x, b.y, b.z, b.w};
            short8v h, l;
#pragma unroll
            for (int e = 0; e < 8; ++e) {
                short hh, ll;
                split_bf16(f[e], hh, ll);
                h[e] = hh; l[e] = ll;
            }
            const int mt = row >> 7;
            const int pr = row & 127;
            const int kstep = cc >> 2;        // 32-k tile index
            const int c = cc & 3;
            const int hf = pr >> 6;
            const int r = pr & 63;
            const int rp = r >> 1;
            const int slot = (((r & 1) << 2) | c) ^ (rp & 7);
            const size_t dst = (size_t)(mt * 256 + kstep) * 4096
                             + hf * 2048 + rp * 64 + slot * 8;
            *(short8v*)&Ahp[dst] = h;
            *(short8v*)&Alp[dst] = l;
        }
    } else if (bid < 2048) {
        // W_enc path: 64(k) x 64(n) tile transpose via LDS, emit packed chunks.
        const int id = bid - 1024;
        const int kstep64 = id >> 3;
        const int k0 = kstep64 * 64;
        const int n0 = (id & 7) * 64;
        {
            const int kr = t >> 2;
            const int cb = (t & 3) * 16;
#pragma unroll
            for (int j = 0; j < 4; ++j) {
                float4 v = *(const float4*)&W_enc[(size_t)(k0 + kr) * F_SZ + n0 + cb + j * 4];
                tile[kr][cb + j * 4 + 0] = v.x;
                tile[kr][cb + j * 4 + 1] = v.y;
                tile[kr][cb + j * 4 + 2] = v.z;
                tile[kr][cb + j * 4 + 3] = v.w;
            }
        }
        __syncthreads();
        const int n = t >> 2;
#pragma unroll
        for (int cc2 = 0; cc2 < 2; ++cc2) {
            const int ch = (t & 3) * 2 + cc2;   // chunk within 64-k (0..7)
            short8v h, l;
#pragma unroll
            for (int e = 0; e < 8; ++e) {
                short hh, ll;
                split_bf16(tile[ch * 8 + e][n], hh, ll);
                h[e] = hh; l[e] = ll;
            }
            const int nrow = n0 + n;
            const int k32 = kstep64 * 2 + (ch >> 2);
            const int c = ch & 3;
            const int nt_ = nrow >> 7;
            const int pr = nrow & 127;
            const int hf = pr >> 6;
            const int r = pr & 63;
            const int rp = r >> 1;
            const int slot = (((r & 1) << 2) | c) ^ (rp & 7);
            const size_t dst = (size_t)(nt_ * 256 + k32) * 4096
                             + hf * 2048 + rp * 64 + slot * 8;
            *(short8v*)&Bhp[dst] = h;
            *(short8v*)&Blp[dst] = l;
        }
    } else {
        // W_fc path: unchanged layout (Wth/Wtl [c][k])
        const int id = bid - 2048;
        const int k0 = (id & 7) * 64;
        const int c0 = (id >> 3) * 64;
        for (int idx = t; idx < 64 * 64; idx += 256) {
            const int kr = idx >> 6;
            const int cc = idx & 63;
            tile[kr][cc] = (c0 + cc < C_SZ) ? W_fc[(size_t)(k0 + kr) * C_SZ + c0 + cc] : 0.0f;
        }
        __syncthreads();
        const int crow = t >> 2;
#pragma unroll
        for (int cc2 = 0; cc2 < 2; ++cc2) {
            const int ch = (t & 3) * 2 + cc2;
            short8v h, l;
#pragma unroll
            for (int e = 0; e < 8; ++e) {
                short hh, ll;
                split_bf16(tile[ch * 8 + e][crow], hh, ll);
                h[e] = hh; l[e] = ll;
            }
            size_t off = (size_t)(c0 + crow) * F_SZ + k0 + ch * 8;
            *(short8v*)&Wth[off] = h;
            *(short8v*)&Wtl[off] = l;
        }
    }
}

// ---------------------------------------------------------------------------
// gemm_ws128_v5 (R14): deep-pipelined 8-phase-style schedule.
// 128x128 tile, BK=32, 64 K-steps, 4 LDS buffers (4 x 32 KB), prefetch
// depth 3, ONE barrier per step, steady vmcnt(8) (2 steps of loads stay in
// flight across barriers — T4), stage-issue right after the barrier,
// 12 ds_read + 24 MFMA per step under setprio (T5).
// Per-accumulator MFMA order identical to v3/v4 -> bit-identical results.
// grid (4,16,4) x 512 threads.
// ---------------------------------------------------------------------------
#define V5_MFMA(PAH, PAL, PBH, PBL)                                          \
    do {                                                                     \
        bf16x8 ah[4], al[4], bh_[2], bl_[2];                                 \
        _Pragma("unroll")                                                    \
        for (int f = 0; f < 4; ++f) {                                        \
            ah[f] = *(const bf16x8*)&(PAH)[aoff[f]];                         \
            al[f] = *(const bf16x8*)&(PAL)[aoff[f]];                         \
        }                                                                    \
        _Pragma("unroll")                                                    \
        for (int g = 0; g < 2; ++g) {                                        \
            bh_[g] = *(const bf16x8*)&(PBH)[boff[g]];                        \
            bl_[g] = *(const bf16x8*)&(PBL)[boff[g]];                        \
        }                                                                    \
        __builtin_amdgcn_s_setprio(1);                                       \
        _Pragma("unroll")                                                    \
        for (int f = 0; f < 4; ++f)                                          \
            _Pragma("unroll")                                                \
            for (int g = 0; g < 2; ++g)                                      \
                acc[f][g] = MFMA_BF16(ah[f], bh_[g], acc[f][g], 0, 0, 0);    \
        _Pragma("unroll")                                                    \
        for (int f = 0; f < 4; ++f)                                          \
            _Pragma("unroll")                                                \
            for (int g = 0; g < 2; ++g)                                      \
                acc[f][g] = MFMA_BF16(ah[f], bl_[g], acc[f][g], 0, 0, 0);    \
        _Pragma("unroll")                                                    \
        for (int f = 0; f < 4; ++f)                                          \
            _Pragma("unroll")                                                \
            for (int g = 0; g < 2; ++g)                                      \
                acc[f][g] = MFMA_BF16(al[f], bh_[g], acc[f][g], 0, 0, 0);    \
        __builtin_amdgcn_s_setprio(0);                                       \
    } while (0)

#define V5_STEP(BI, SD, SW, VMLIT)                                           \
    do {                                                                     \
        asm volatile("s_waitcnt vmcnt(" VMLIT ")" ::: "memory");             \
        fence_barrier();                                                     \
        {                                                                    \
            const short* gg = gsrc0 + (size_t)(SW) * 4096;                   \
            gl_lds16(gg, SD);                                                \
            gl_lds16(gg + 512, (SD) + 512);                                  \
            gl_lds16(gg + 1024, (SD) + 1024);                                \
            gl_lds16(gg + 1536, (SD) + 1536);                                \
        }                                                                    \
        V5_MFMA(SAh[BI], SAl[BI], SBh[BI], SBl[BI]);                         \
    } while (0)

#define V5_STEPN(BI, VMLIT)                                                  \
    do {                                                                     \
        asm volatile("s_waitcnt vmcnt(" VMLIT ")" ::: "memory");             \
        fence_barrier();                                                     \
        V5_MFMA(SAh[BI], SAl[BI], SBh[BI], SBl[BI]);                         \
    } while (0)

__global__ __launch_bounds__(512, 1) void gemm_ws128_v5(
    const short* __restrict__ Ahp, const short* __restrict__ Alp,
    const short* __restrict__ Bhp, const short* __restrict__ Blp,
    float* __restrict__ P)
{
    __shared__ __align__(16) short SAh[4][4096];
    __shared__ __align__(16) short SAl[4][4096];
    __shared__ __align__(16) short SBh[4][4096];
    __shared__ __align__(16) short SBl[4][4096];

    const int t = threadIdx.x;
    const int lane = t & 63;
    const int wave = t >> 6;

    // XCD-aware bijective swizzle (flat id, nwg = 256)
    const int flat = blockIdx.x + 4 * blockIdx.y + 64 * blockIdx.z;
    const int logical = (flat & 7) * 32 + (flat >> 3);
    const int nt = logical & 3;
    const int mt = (logical >> 2) & 15;
    const int ks = logical >> 6;

    const int m0 = mt * 128;
    const int n0 = nt * 128;

    // staging role: arr = which LDS array, half = which 64 rows (2 KB piece)
    const int arr = wave >> 1;
    const int half = wave & 1;
    const short* gtile =
        (arr == 0) ? Ahp + (size_t)(mt * 256) * 4096 :
        (arr == 1) ? Alp + (size_t)(mt * 256) * 4096 :
        (arr == 2) ? Bhp + (size_t)(nt * 256) * 4096 :
                     Blp + (size_t)(nt * 256) * 4096;
    const short* gsrc0 = gtile + (size_t)(ks * 64) * 4096 + half * 2048 + lane * 8;

    short* abase =
        (arr == 0) ? &SAh[0][0] : (arr == 1) ? &SAl[0][0] :
        (arr == 2) ? &SBh[0][0] : &SBl[0][0];
    short* sd0 = abase + 0 * 4096 + half * 2048;
    short* sd1 = abase + 1 * 4096 + half * 2048;
    short* sd2 = abase + 2 * 4096 + half * 2048;
    short* sd3 = abase + 3 * 4096 + half * 2048;

    // compute role: wave tile 64 rows x 32 cols
    const int wr = wave >> 2;
    const int wc = wave & 3;
    const int mo = wr * 64;
    const int no = wc * 32;
    const int lr = lane & 15;
    const int lkg = lane >> 4;
    int aoff[4], boff[2];
#pragma unroll
    for (int f = 0; f < 4; ++f) {
        const int R = mo + 16 * f + lr;
        const int r = R & 63;
        const int rp = r >> 1;
        aoff[f] = (R >> 6) * 2048 + rp * 64
                + (((((r & 1) << 2) | lkg)) ^ (rp & 7)) * 8;
    }
#pragma unroll
    for (int g = 0; g < 2; ++g) {
        const int R = no + 16 * g + lr;
        const int r = R & 63;
        const int rp = r >> 1;
        boff[g] = (R >> 6) * 2048 + rp * 64
                + (((((r & 1) << 2) | lkg)) ^ (rp & 7)) * 8;
    }

    f32x4 acc[4][2] = {};

    // prologue: stage steps 0,1,2 into buffers 0,1,2 (12 loads in flight)
    {
        gl_lds16(gsrc0,        sd0);
        gl_lds16(gsrc0 + 512,  sd0 + 512);
        gl_lds16(gsrc0 + 1024, sd0 + 1024);
        gl_lds16(gsrc0 + 1536, sd0 + 1536);
        const short* g1 = gsrc0 + 4096;
        gl_lds16(g1,        sd1);
        gl_lds16(g1 + 512,  sd1 + 512);
        gl_lds16(g1 + 1024, sd1 + 1024);
        gl_lds16(g1 + 1536, sd1 + 1536);
        const short* g2 = gsrc0 + 8192;
        gl_lds16(g2,        sd2);
        gl_lds16(g2 + 512,  sd2 + 512);
        gl_lds16(g2 + 1024, sd2 + 1024);
        gl_lds16(g2 + 1536, sd2 + 1536);
    }

    // main: steps 0..59 (steady state: vmcnt(8), issue s+3 after barrier)
    for (int s4 = 0; s4 < 15; ++s4) {
        const int sb = s4 * 4;
        V5_STEP(0, sd3, sb + 3, "8");
        V5_STEP(1, sd0, sb + 4, "8");
        V5_STEP(2, sd1, sb + 5, "8");
        V5_STEP(3, sd2, sb + 6, "8");
    }
    // peeled tail: s = 60..63
    V5_STEP (0, sd3, 63, "8");    // s=60 (issues step 63)
    V5_STEPN(1, "8");             // s=61
    V5_STEPN(2, "4");             // s=62
    V5_STEPN(3, "0");             // s=63

    float* Pout = P + (size_t)ks * (2048u * 512u);
#pragma unroll
    for (int f = 0; f < 4; ++f)
#pragma unroll
        for (int g = 0; g < 2; ++g) {
            const int col  = n0 + no + 16 * g + (lane & 15);
            const int row0 = m0 + mo + 16 * f + (lane >> 4) * 4;
#pragma unroll
            for (int r = 0; r < 4; ++r)
                Pout[(size_t)(row0 + r) * F_SZ + col] = acc[f][g][r];
        }
}

// ---------------------------------------------------------------------------
// reduce_feats4: sum the 4 split-K P slices once -> feats fp32 + Fh/Fl
// bf16 split. Same summation order as before (bit-identical).
// ---------------------------------------------------------------------------
__global__ __launch_bounds__(256) void reduce_feats4(
    const float* __restrict__ P, float* __restrict__ feats,
    short* __restrict__ Fh, short* __restrict__ Fl)
{
    const int i4 = blockIdx.x * 256 + threadIdx.x;
    float4 a = ((const float4*)P)[i4];
#pragma unroll
    for (int sl = 1; sl < 4; ++sl) {
        float4 b = ((const float4*)(P + (size_t)sl * (2048u * 512u)))[i4];
        a.x += b.x; a.y += b.y; a.z += b.z; a.w += b.w;
    }
    ((float4*)feats)[i4] = a;
    float v[4] = {a.x, a.y, a.z, a.w};
    short4v h, l;
    short hh, ll;
#pragma unroll
    for (int e = 0; e < 4; ++e) {
        split_bf16(v[e], hh, ll); h[e] = hh; l[e] = ll;
    }
    ((short4v*)Fh)[i4] = h;
    ((short4v*)Fl)[i4] = l;
}

// ---------------------------------------------------------------------------
// fc_logits3: logits = feats @ W_fc^T + bias from bf16 Fh/Fl (L2-resident)
// with fused packed-atomicMax masked argmax. Double-buffered 64 KB LDS
// (2 blocks/CU), counted-vmcnt pipeline. grid (6,32).
// ---------------------------------------------------------------------------
__global__ __launch_bounds__(256, 2) void fc_logits3(
    const short* __restrict__ Ah, const short* __restrict__ Al,
    const short* __restrict__ Bh_g, const short* __restrict__ Bl_g,
    const float* __restrict__ bias, const float* __restrict__ partial_Y,
    float* __restrict__ logits, unsigned long long* __restrict__ labPack)
{
    __shared__ __align__(16) short dAh[2][4096];
    __shared__ __align__(16) short dAl[2][4096];
    __shared__ __align__(16) short dBh[2][4096];
    __shared__ __align__(16) short dBl[2][4096];

    const int t = threadIdx.x;
    const int lane = t & 63;
    const int wave = t >> 6;
    const int n0 = blockIdx.x * 64;
    const int m0 = blockIdx.y * 64;

    const int lrow8 = lane >> 3;
    const int colOff = ((lane & 7) ^ lrow8) * 8;

    const short* gsrc = (wave == 0) ? Ah : (wave == 1) ? Al
                      : (wave == 2) ? Bh_g : Bl_g;
    const int rbase = (wave < 2) ? m0 : n0;
    short* lb[2];
    lb[0] = (wave == 0) ? dAh[0] : (wave == 1) ? dAl[0] : (wave == 2) ? dBh[0] : dBl[0];
    lb[1] = (wave == 0) ? dAh[1] : (wave == 1) ? dAl[1] : (wave == 2) ? dBh[1] : dBl[1];
    const short* gbase = gsrc + (size_t)(rbase + lrow8) * F_SZ + colOff;

    const int mo = (wave >> 1) * 32;
    const int no = (wave & 1) * 32;
    const int lr = lane & 15;
    const int lkg = lane >> 4;
    const int x7 = lr & 7;
    const int sl0 = (0 + lkg) ^ x7;
    const int sl1 = (4 + lkg) ^ x7;
    const int ra0 = (mo + lr) * 64,      ra1 = (mo + 16 + lr) * 64;
    const int rb0 = (no + lr) * 64,      rb1 = (no + 16 + lr) * 64;
    const int a00 = ra0 + sl0 * 8, a01 = ra0 + sl1 * 8;
    const int a10 = ra1 + sl0 * 8, a11 = ra1 + sl1 * 8;
    const int b00 = rb0 + sl0 * 8, b01 = rb0 + sl1 * 8;
    const int b10 = rb1 + sl0 * 8, b11 = rb1 + sl1 * 8;

    f32x4 acc[2][2] = {};

#pragma unroll
    for (int j = 0; j < 8; ++j)
        gl_lds16(gbase + (size_t)(8 * j) * F_SZ, lb[0] + j * 512);

    int buf = 0;
    for (int s = 0; s < 8; ++s) {
        if (s + 1 < 8) {
            short* dst = lb[buf ^ 1];
            const short* g = gbase + (s + 1) * 64;
#pragma unroll
            for (int j = 0; j < 8; ++j)
                gl_lds16(g + (size_t)(8 * j) * F_SZ, dst + j * 512);
            asm volatile("s_waitcnt vmcnt(8)" ::: "memory");
        } else {
            asm volatile("s_waitcnt vmcnt(0)" ::: "memory");
        }
        fence_barrier();
        __builtin_amdgcn_s_setprio(1);
        {
            const short* sAh = dAh[buf];
            const short* sAl = dAl[buf];
            const short* sBh = dBh[buf];
            const short* sBl = dBl[buf];
            MFMA_BLOCK(a00, a10, b00, b10);
            MFMA_BLOCK(a01, a11, b01, b11);
        }
        __builtin_amdgcn_s_setprio(0);
        fence_barrier();
        buf ^= 1;
    }

    const bool doArg = (m0 < B_SZ);
#pragma unroll
    for (int f = 0; f < 2; ++f) {
#pragma unroll
        for (int r = 0; r < 4; ++r) {
            const int row = m0 + mo + f * 16 + (lane >> 4) * 4 + r;
            unsigned long long best = 0;
#pragma unroll
            for (int g = 0; g < 2; ++g) {
                const int col = n0 + no + g * 16 + (lane & 15);
                if (col < C_SZ) {
                    const float v = acc[f][g][r] + bias[col];
                    logits[(size_t)row * C_SZ + col] = v;
                    if (doArg && partial_Y[(size_t)row * C_SZ + col] != 0.0f) {
                        unsigned long long p = ((unsigned long long)f2key(v) << 32)
                                             | (unsigned long long)(0xFFFFFFFFu - (unsigned)col);
                        if (p > best) best = p;
                    }
                }
            }
            if (doArg) {
#pragma unroll
                for (int m = 1; m < 16; m <<= 1) {
                    unsigned long long o = __shfl_xor(best, m);
                    if (o > best) best = o;
                }
                if ((lane & 15) == 0 && best != 0)
                    atomicMax(&labPack[row], best);
            }
        }
    }
}

// ---------------------------------------------------------------------------
// proto_scores_fused: per class c —
//   phase 1 (wave 0): ballot-decode labPack into ordered rowlist
//   phase 2: EMA over matching rows (order preserved), L2 renorm, write proto
//   phase 3: scores row, coalesced; shuffle-reduce. grid 345, 512 threads.
// ---------------------------------------------------------------------------
__global__ __launch_bounds__(512) void proto_scores_fused(
    const unsigned long long* __restrict__ labPack,
    const float* __restrict__ feats_q,
    const float* __restrict__ proto,
    const short* __restrict__ Wth, const short* __restrict__ Wtl,
    const float* __restrict__ b_fc,
    float* __restrict__ new_proto, float* __restrict__ scores,
    float* __restrict__ labels_f)
{
    __shared__ int rowlist[B_SZ];
    __shared__ int mcount_s;
    __shared__ float nprow[F_SZ];
    __shared__ float red[8];
    __shared__ float rinv_s;
    const int c = blockIdx.x;
    const int t = threadIdx.x;
    const int lane = t & 63;
    const int w = t >> 6;

    if (c == 0) {
#pragma unroll
        for (int j = 0; j < 2; ++j) {
            const int i = t + j * 512;
            int li = (int)(0xFFFFFFFFu - (unsigned)(labPack[i] & 0xFFFFFFFFull));
            labels_f[i] = (float)li;
        }
    }

    if (w == 0) {
        int k = 0;
#pragma unroll
        for (int ch = 0; ch < 16; ++ch) {
            unsigned long long pk = labPack[ch * 64 + lane];
            int li = (int)(0xFFFFFFFFu - (unsigned)(pk & 0xFFFFFFFFull));
            unsigned long long mask = __ballot(li == c);
            if (lane == 0) {
                while (mask) {
                    int p = __builtin_ctzll(mask);
                    mask &= mask - 1;
                    rowlist[k++] = ch * 64 + p;
                }
            }
            k = __shfl(k, 0);
        }
        if (lane == 0) mcount_s = k;
    }
    __syncthreads();
    const int m = mcount_s;

    float val = proto[(size_t)c * F_SZ + t];
    for (int k = 0; k < m; ++k)
        val = PROTO_W * val + (1.0f - PROTO_W) * feats_q[(size_t)rowlist[k] * F_SZ + t];

    float sq = val * val;
#pragma unroll
    for (int off = 32; off; off >>= 1) sq += __shfl_down(sq, off);
    if ((t & 63) == 0) red[t >> 6] = sq;
    __syncthreads();
    if (t == 0) {
        float s = 0.0f;
#pragma unroll
        for (int ww = 0; ww < 8; ++ww) s += red[ww];
        rinv_s = 1.0f / sqrtf(s);
    }
    __syncthreads();
    const float v = val * rinv_s;
    new_proto[(size_t)c * F_SZ + t] = v;
    nprow[t] = v;
    __syncthreads();

    float np8[8];
#pragma unroll
    for (int j = 0; j < 8; ++j) np8[j] = nprow[lane * 8 + j];
    for (int col = w; col < C_SZ; col += 8) {
        const short8v h = *(const short8v*)&Wth[(size_t)col * F_SZ + lane * 8];
        const short8v l = *(const short8v*)&Wtl[(size_t)col * F_SZ + lane * 8];
        float p = 0.0f;
#pragma unroll
        for (int j = 0; j < 8; ++j)
            p += np8[j] * (bf16_f32(h[j]) + bf16_f32(l[j]));
#pragma unroll
        for (int off = 32; off; off >>= 1) p += __shfl_down(p, off);
        if (lane == 0) scores[(size_t)c * C_SZ + col] = p + b_fc[col];
    }
}

// ===========================================================================
// OLD-path kernels (R6-proven fallback; used when ws < WS2_NEED)
// ===========================================================================
__global__ __launch_bounds__(256) void convert_all(
    const float* __restrict__ img_q, const float* __restrict__ img_q1,
    const float* __restrict__ W_enc, const float* __restrict__ W_fc,
    short* __restrict__ Xh, short* __restrict__ Xl,
    short* __restrict__ Wh, short* __restrict__ Wl,
    short* __restrict__ Wth, short* __restrict__ Wtl,
    unsigned long long* __restrict__ labPack)
{
    __shared__ float tile[64][65];
    const int bid = blockIdx.x;
    const int t = threadIdx.x;

    if (labPack && bid < 4)
        labPack[bid * 256 + t] = 0ull;

    if (bid < 1024) {
        const int HALF = (B_SZ * D_SZ) / 4;
        const int total = 2 * HALF;
        for (int i4 = bid * 256 + t; i4 < total; i4 += 1024 * 256) {
            float4 v = (i4 < HALF) ? ((const float4*)img_q)[i4]
                                   : ((const float4*)img_q1)[i4 - HALF];
            short4v h, l;
            short hh, ll;
            split_bf16(v.x, hh, ll); h.x = hh; l.x = ll;
            split_bf16(v.y, hh, ll); h.y = hh; l.y = ll;
            split_bf16(v.z, hh, ll); h.z = hh; l.z = ll;
            split_bf16(v.w, hh, ll); h.w = hh; l.w = ll;
            ((short4v*)Xh)[i4] = h;
            ((short4v*)Xl)[i4] = l;
        }
    } else if (bid < 2048) {
        const int id = bid - 1024;
        const int k0 = (id >> 3) * 64;
        const int n0 = (id & 7) * 64;
        {
            const int kr = t >> 2;
            const int cb = (t & 3) * 16;
#pragma unroll
            for (int j = 0; j < 4; ++j) {
                float4 v = *(const float4*)&W_enc[(size_t)(k0 + kr) * F_SZ + n0 + cb + j * 4];
                tile[kr][cb + j * 4 + 0] = v.x;
                tile[kr][cb + j * 4 + 1] = v.y;
                tile[kr][cb + j * 4 + 2] = v.z;
                tile[kr][cb + j * 4 + 3] = v.w;
            }
        }
        __syncthreads();
        const int n = t >> 2;
#pragma unroll
        for (int cc = 0; cc < 2; ++cc) {
            const int ch = (t & 3) * 2 + cc;
            short8v h, l;
#pragma unroll
            for (int e = 0; e < 8; ++e) {
                short hh, ll;
                split_bf16(tile[ch * 8 + e][n], hh, ll);
                h[e] = hh; l[e] = ll;
            }
            size_t off = (size_t)(n0 + n) * D_SZ + k0 + ch * 8;
            *(short8v*)&Wh[off] = h;
            *(short8v*)&Wl[off] = l;
        }
    } else {
        const int id = bid - 2048;
        const int k0 = (id & 7) * 64;
        const int c0 = (id >> 3) * 64;
        for (int idx = t; idx < 64 * 64; idx += 256) {
            const int kr = idx >> 6;
            const int cc = idx & 63;
            tile[kr][cc] = (c0 + cc < C_SZ) ? W_fc[(size_t)(k0 + kr) * C_SZ + c0 + cc] : 0.0f;
        }
        __syncthreads();
        const int crow = t >> 2;
#pragma unroll
        for (int cc2 = 0; cc2 < 2; ++cc2) {
            const int ch = (t & 3) * 2 + cc2;
            short8v h, l;
#pragma unroll
            for (int e = 0; e < 8; ++e) {
                short hh, ll;
                split_bf16(tile[ch * 8 + e][crow], hh, ll);
                h[e] = hh; l[e] = ll;
            }
            size_t off = (size_t)(c0 + crow) * F_SZ + k0 + ch * 8;
            *(short8v*)&Wth[off] = h;
            *(short8v*)&Wtl[off] = l;
        }
    }
}

__global__ __launch_bounds__(256, 1) void gemm_ws128(
    const short* __restrict__ Xh, const short* __restrict__ Xl,
    const short* __restrict__ Wh, const short* __restrict__ Wl,
    float* __restrict__ P, int ksteps)
{
    __shared__ __align__(16) short sAh[2][8192];
    __shared__ __align__(16) short sAl[2][8192];
    __shared__ __align__(16) short sBh[2][8192];
    __shared__ __align__(16) short sBl[2][8192];

    const int t = threadIdx.x;
    const int lane = t & 63;
    const int wave = t >> 6;
    const int nt = blockIdx.x;
    const int mt = blockIdx.y;
    const int ks = blockIdx.z;
    const int m0 = mt * 128;
    const int n0 = nt * 128;
    const int kbase = ks * ksteps * 64;

    const short* gbase =
        (wave == 0) ? Xh + (size_t)m0 * D_SZ :
        (wave == 1) ? Xl + (size_t)m0 * D_SZ :
        (wave == 2) ? Wh + (size_t)n0 * D_SZ :
                      Wl + (size_t)n0 * D_SZ;
    short* lb[2];
    lb[0] = (wave == 0) ? sAh[0] : (wave == 1) ? sAl[0] : (wave == 2) ? sBh[0] : sBl[0];
    lb[1] = (wave == 0) ? sAh[1] : (wave == 1) ? sAl[1] : (wave == 2) ? sBh[1] : sBl[1];
    const int lrow8 = lane >> 3;
    const int gchunkOff = ((lane & 7) ^ lrow8) * 8;
    const short* gsrc = gbase + (size_t)lrow8 * D_SZ + kbase + gchunkOff;

    const int mo = (wave >> 1) * 64;
    const int no = (wave & 1) * 64;
    const int lr = lane & 15;
    const int lkg = lane >> 4;
    const int x7 = lr & 7;
    const int sl0 = lkg ^ x7;
    const int sl1 = (4 + lkg) ^ x7;
    int aoff[4], boff[4];
#pragma unroll
    for (int f = 0; f < 4; ++f) {
        aoff[f] = (mo + 16 * f + lr) * 64;
        boff[f] = (no + 16 * f + lr) * 64;
    }

    f32x4 acc[4][4] = {};

#pragma unroll
    for (int j = 0; j < 16; ++j)
        gl_lds16(gsrc + (size_t)(8 * j) * D_SZ, lb[0] + j * 512);

    int buf = 0;
    for (int s = 0; s < ksteps; ++s) {
        if (s + 1 < ksteps) {
            short* dst = lb[buf ^ 1];
            const short* g = gsrc + (s + 1) * 64;
#pragma unroll
            for (int j = 0; j < 16; ++j)
                gl_lds16(g + (size_t)(8 * j) * D_SZ, dst + j * 512);
            asm volatile("s_waitcnt vmcnt(16)" ::: "memory");
        } else {
            asm volatile("s_waitcnt vmcnt(0)" ::: "memory");
        }
        fence_barrier();

        __builtin_amdgcn_s_setprio(1);
        {
            const short* pAh = sAh[buf];
            const short* pAl = sAl[buf];
            const short* pBh = sBh[buf];
            const short* pBl = sBl[buf];
#pragma unroll
            for (int ksub = 0; ksub < 2; ++ksub) {
                const int sl = ksub ? sl1 : sl0;
                bf16x8 ah[4], al[4], bh[4], blo[4];
#pragma unroll
                for (int f = 0; f < 4; ++f) {
                    ah[f]  = *(const bf16x8*)&pAh[aoff[f] + sl * 8];
                    al[f]  = *(const bf16x8*)&pAl[aoff[f] + sl * 8];
                }
#pragma unroll
                for (int g = 0; g < 4; ++g) {
                    bh[g]  = *(const bf16x8*)&pBh[boff[g] + sl * 8];
                    blo[g] = *(const bf16x8*)&pBl[boff[g] + sl * 8];
                }
#pragma unroll
                for (int f = 0; f < 4; ++f)
#pragma unroll
                    for (int g = 0; g < 4; ++g)
                        acc[f][g] = MFMA_BF16(ah[f], bh[g], acc[f][g], 0, 0, 0);
#pragma unroll
                for (int f = 0; f < 4; ++f)
#pragma unroll
                    for (int g = 0; g < 4; ++g)
                        acc[f][g] = MFMA_BF16(ah[f], blo[g], acc[f][g], 0, 0, 0);
#pragma unroll
                for (int f = 0; f < 4; ++f)
#pragma unroll
                    for (int g = 0; g < 4; ++g)
                        acc[f][g] = MFMA_BF16(al[f], bh[g], acc[f][g], 0, 0, 0);
            }
        }
        __builtin_amdgcn_s_setprio(0);
        fence_barrier();
        buf ^= 1;
    }

    float* Pout = P + (size_t)ks * (2048u * 512u);
#pragma unroll
    for (int f = 0; f < 4; ++f)
#pragma unroll
        for (int g = 0; g < 4; ++g) {
            const int col  = n0 + no + 16 * g + (lane & 15);
            const int row0 = m0 + mo + 16 * f + (lane >> 4) * 4;
#pragma unroll
            for (int r = 0; r < 4; ++r)
                Pout[(size_t)(row0 + r) * F_SZ + col] = acc[f][g][r];
        }
}

__global__ __launch_bounds__(256) void reduce_feats_split(
    const float* __restrict__ P, float* __restrict__ feats,
    short* __restrict__ Fh, short* __restrict__ Fl,
    const float* __restrict__ W_fc,
    short* __restrict__ Wth, short* __restrict__ Wtl)
{
    const int bid = blockIdx.x;
    const int t = threadIdx.x;
    if (bid < 1024) {
        const int n4 = (2048 * 512) / 4;
        const float* P1 = P + 2048 * 512;
        for (int i4 = bid * 256 + t; i4 < n4; i4 += 1024 * 256) {
            float4 a = ((const float4*)P)[i4];
            float4 b = ((const float4*)P1)[i4];
            float v[4] = {a.x + b.x, a.y + b.y, a.z + b.z, a.w + b.w};
            short4v h, l;
            short hh, ll;
#pragma unroll
            for (int e = 0; e < 4; ++e) {
                feats[i4 * 4 + e] = v[e];
                split_bf16(v[e], hh, ll); h[e] = hh; l[e] = ll;
            }
            ((short4v*)Fh)[i4] = h;
            ((short4v*)Fl)[i4] = l;
        }
    } else {
        __shared__ float tile[64][65];
        const int id = bid - 1024;
        const int k0 = (id & 7) * 64;
        const int c0 = (id >> 3) * 64;
        for (int idx = t; idx < 64 * 64; idx += 256) {
            const int kr = idx >> 6;
            const int cc = idx & 63;
            tile[kr][cc] = (c0 + cc < C_SZ) ? W_fc[(size_t)(k0 + kr) * C_SZ + c0 + cc] : 0.0f;
        }
        __syncthreads();
        const int crow = t >> 2;
#pragma unroll
        for (int cc2 = 0; cc2 < 2; ++cc2) {
            const int ch = (t & 3) * 2 + cc2;
            short8v h, l;
#pragma unroll
            for (int e = 0; e < 8; ++e) {
                short hh, ll;
                split_bf16(tile[ch * 8 + e][crow], hh, ll);
                h[e] = hh; l[e] = ll;
            }
            size_t off = (size_t)(c0 + crow) * F_SZ + k0 + ch * 8;
            *(short8v*)&Wth[off] = h;
            *(short8v*)&Wtl[off] = l;
        }
    }
}

__global__ __launch_bounds__(256) void gemm_fc(
    const short* __restrict__ Ah, const short* __restrict__ Al,
    const short* __restrict__ Bh, const short* __restrict__ Bl,
    const float* __restrict__ bias, float* __restrict__ Cout, int M)
{
    __shared__ __align__(16) short sAh[4096];
    __shared__ __align__(16) short sAl[4096];
    __shared__ __align__(16) short sBh[4096];
    __shared__ __align__(16) short sBl[4096];

    const int t = threadIdx.x;
    const int lane = t & 63;
    const int wave = t >> 6;
    const int n0 = blockIdx.x * 64;
    const int m0 = blockIdx.y * 64;

    const int lrow8 = lane >> 3;
    const int colOff = ((lane & 7) ^ lrow8) * 8;

    short* lbase = (wave == 0) ? sAh : (wave == 1) ? sAl : (wave == 2) ? sBh : sBl;
    const short* gA = (wave == 1) ? Al : Ah;
    const short* gB = (wave == 3) ? Bl : Bh;
    const bool isA = wave < 2;

    const int mo = (wave >> 1) * 32;
    const int no = (wave & 1) * 32;
    const int lr = lane & 15;
    const int lkg = lane >> 4;
    const int x7 = lr & 7;
    const int sl0 = (0 + lkg) ^ x7;
    const int sl1 = (4 + lkg) ^ x7;
    const int ra0 = (mo + lr) * 64,      ra1 = (mo + 16 + lr) * 64;
    const int rb0 = (no + lr) * 64,      rb1 = (no + 16 + lr) * 64;
    const int a00 = ra0 + sl0 * 8, a01 = ra0 + sl1 * 8;
    const int a10 = ra1 + sl0 * 8, a11 = ra1 + sl1 * 8;
    const int b00 = rb0 + sl0 * 8, b01 = rb0 + sl1 * 8;
    const int b10 = rb1 + sl0 * 8, b11 = rb1 + sl1 * 8;

    f32x4 acc[2][2] = {};

    for (int s = 0; s < 8; ++s) {
        __syncthreads();
        if (isA) {
#pragma unroll
            for (int j = 0; j < 8; ++j) {
                int row = m0 + lrow8 + 8 * j;
                if (row > M - 1) row = M - 1;
                gl_lds16(gA + (size_t)row * F_SZ + s * 64 + colOff, lbase + j * 512);
            }
        } else {
#pragma unroll
            for (int j = 0; j < 8; ++j) {
                int row = n0 + lrow8 + 8 * j;
                gl_lds16(gB + (size_t)row * F_SZ + s * 64 + colOff, lbase + j * 512);
            }
        }
        __syncthreads();
        MFMA_BLOCK(a00, a10, b00, b10);
        MFMA_BLOCK(a01, a11, b01, b11);
    }

#pragma unroll
    for (int f = 0; f < 2; ++f)
#pragma unroll
        for (int g = 0; g < 2; ++g) {
            const int col  = n0 + no + g * 16 + (lane & 15);
            if (col >= C_SZ) continue;
            const float bb = bias[col];
            const int row0 = m0 + mo + f * 16 + (lane >> 4) * 4;
#pragma unroll
            for (int r = 0; r < 4; ++r) {
                const int row = row0 + r;
                if (row < M)
                    Cout[(size_t)row * C_SZ + col] = acc[f][g][r] + bb;
            }
        }
}

__global__ __launch_bounds__(64) void argmax_labels(
    const float* __restrict__ logits, const float* __restrict__ partial_Y,
    float* __restrict__ labels_f)
{
    const int i = blockIdx.x;
    const int lane = threadIdx.x;
    float best = -FLT_MAX;
    int bidx = C_SZ;
    for (int c = lane; c < C_SZ; c += 64) {
        if (partial_Y[(size_t)i * C_SZ + c] != 0.0f) {
            float v = logits[(size_t)i * C_SZ + c];
            if (v > best || (v == best && c < bidx)) { best = v; bidx = c; }
        }
    }
#pragma unroll
    for (int off = 32; off; off >>= 1) {
        float ov = __shfl_down(best, off);
        int oi = __shfl_down(bidx, off);
        if (ov > best || (ov == best && oi < bidx)) { best = ov; bidx = oi; }
    }
    if (lane == 0) labels_f[i] = (float)bidx;
}

__global__ __launch_bounds__(512) void proto_update(
    const float* __restrict__ labels_f, const float* __restrict__ feats_q,
    const float* __restrict__ proto, float* __restrict__ new_proto,
    short* __restrict__ NPh, short* __restrict__ NPl)
{
    __shared__ int lab[B_SZ];
    __shared__ float red[8];
    __shared__ float rinv_s;
    const int c = blockIdx.x;
    const int t = threadIdx.x;
    for (int i = t; i < B_SZ; i += 512) lab[i] = (int)labels_f[i];
    __syncthreads();
    float val = proto[(size_t)c * F_SZ + t];
    for (int i = 0; i < B_SZ; ++i) {
        if (lab[i] == c)
            val = PROTO_W * val + (1.0f - PROTO_W) * feats_q[(size_t)i * F_SZ + t];
    }
    float sq = val * val;
#pragma unroll
    for (int off = 32; off; off >>= 1) sq += __shfl_down(sq, off);
    if ((t & 63) == 0) red[t >> 6] = sq;
    __syncthreads();
    if (t == 0) {
        float s = 0.0f;
#pragma unroll
        for (int w = 0; w < 8; ++w) s += red[w];
        rinv_s = 1.0f / sqrtf(s);
    }
    __syncthreads();
    const float v = val * rinv_s;
    new_proto[(size_t)c * F_SZ + t] = v;
    if (NPh) {
        short hh, ll;
        split_bf16(v, hh, ll);
        NPh[(size_t)c * F_SZ + t] = hh;
        NPl[(size_t)c * F_SZ + t] = ll;
    }
}

// ---------------------------------------------------------------------------
extern "C" void kernel_launch(void* const* d_in, const int* in_sizes, int n_in,
                              void* d_out, int out_size, void* d_ws, size_t ws_size,
                              hipStream_t stream)
{
    const float* img_q     = (const float*)d_in[0];
    const float* img_q1    = (const float*)d_in[1];
    const float* partial_Y = (const float*)d_in[2];
    const float* W_enc     = (const float*)d_in[3];
    const float* W_fc      = (const float*)d_in[4];
    const float* b_fc      = (const float*)d_in[5];
    const float* proto     = (const float*)d_in[6];

    float* out       = (float*)d_out;
    float* logits    = out;            // [2048][345]
    float* new_proto = out + 706560;   // [345][512]
    float* scores    = out + 883200;   // [345][345]
    float* labels_f  = out + 1002225;  // [1024]
    float* feats     = out + 1003249;  // [2048][512]

    char* ws = (char*)d_ws;
    short* Xh = (short*)(ws + WS_XH);
    short* Xl = (short*)(ws + WS_XL);
    short* Wh = (short*)(ws + WS_WH);
    short* Wl = (short*)(ws + WS_WL);
    float* P  = (float*)(ws + WS_P);

    if (ws_size >= (size_t)WS2_NEED) {
        short* Wth = (short*)(ws + WS2_WFH);
        short* Wtl = (short*)(ws + WS2_WFL);
        unsigned long long* labPack = (unsigned long long*)(ws + WS2_LAB);
        // Fh/Fl overlay Xh (dead after gemm; same-stream ordering)
        short* Fh = (short*)(ws + 0u);
        short* Fl = (short*)(ws + 2097152u);

        hipLaunchKernelGGL(convert_pack2, dim3(2096), dim3(256), 0, stream,
                           img_q, img_q1, W_enc, W_fc, Xh, Xl, Wh, Wl, Wth, Wtl,
                           labPack);
        hipLaunchKernelGGL(gemm_ws128_v5, dim3(4, 16, 4), dim3(512), 0, stream,
                           Xh, Xl, Wh, Wl, P);
        hipLaunchKernelGGL(reduce_feats4, dim3(1024), dim3(256), 0, stream,
                           P, feats, Fh, Fl);
        hipLaunchKernelGGL(fc_logits3, dim3(6, 32), dim3(256), 0, stream,
                           Fh, Fl, Wth, Wtl, b_fc, partial_Y, logits, labPack);
        hipLaunchKernelGGL(proto_scores_fused, dim3(345), dim3(512), 0, stream,
                           labPack, feats, proto, Wth, Wtl, b_fc,
                           new_proto, scores, labels_f);
    } else {
        short* Fh  = (short*)(ws + WS_FH);
        short* Fl  = (short*)(ws + WS_FL);
        short* Wth = (short*)(ws + WS_WFH);
        short* Wtl = (short*)(ws + WS_WFL);
        short* NPh = (short*)(ws + WS_NPH);
        short* NPl = (short*)(ws + WS_NPL);

        hipLaunchKernelGGL(convert_all, dim3(2048), dim3(256), 0, stream,
                           img_q, img_q1, W_enc, W_fc, Xh, Xl, Wh, Wl,
                           (short*)nullptr, (short*)nullptr,
                           (unsigned long long*)nullptr);
        hipLaunchKernelGGL(gemm_ws128, dim3(4, 16, 2), dim3(256), 0, stream,
                           Xh, Xl, Wh, Wl, P, 64);
        hipLaunchKernelGGL(reduce_feats_split, dim3(1072), dim3(256), 0, stream,
                           P, feats, Fh, Fl, W_fc, Wth, Wtl);
        hipLaunchKernelGGL(gemm_fc, dim3(6, 32), dim3(256), 0, stream,
                           Fh, Fl, Wth, Wtl, b_fc, logits, 2048);
        hipLaunchKernelGGL(argmax_labels, dim3(1024), dim3(64), 0, stream,
                           logits, partial_Y, labels_f);
        hipLaunchKernelGGL(proto_update, dim3(345), dim3(512), 0, stream,
                           labels_f, feats, proto, new_proto, NPh, NPl);
        hipLaunchKernelGGL(gemm_fc, dim3(6, 6), dim3(256), 0, stream,
                           NPh, NPl, Wth, Wtl, b_fc, scores, C_SZ);
    }
}